// Round 4
// baseline (22548.372 us; speedup 1.0000x reference)
//
#include <hip/hip_runtime.h>
#include <hip/hip_fp16.h>

#define NN 1024

typedef _Float16 v2h __attribute__((ext_vector_type(2)));
typedef unsigned int uint;
typedef unsigned long long u64;
typedef unsigned int u32x4 __attribute__((ext_vector_type(4)));

// Static device scratch.
__device__ __half g_W[16][NN][2048];     // per stage row: [Wih_eff(1024) | Whh(1024)] fp16
__device__ float g_bias[16][NN];         // combined bias fp32
__device__ unsigned g_T[16][NN][32];     // completion tag per (stage, step, producer-WG)
__device__ u64 g_D[16][NN][256];         // h data: u64 = 4×fp16, rows 4i..4i+3
__device__ float g_Hout[8][NN * NN];     // h of odd stages (pre-linear), fp32

__device__ __forceinline__ v2h as_v2h(uint u) {
  union { uint u; v2h h; } c; c.u = u; return c.h;
}
__device__ __forceinline__ uint pk2(float a, float b) {
  union { v2h h; uint u; } c; c.h.x = (_Float16)a; c.h.y = (_Float16)b; return c.u;
}

// full-wave (64-lane) sum via DPP; valid result in lane 63.
__device__ __forceinline__ float dpp_reduce(float v) {
  int t;
  t = __builtin_amdgcn_update_dpp(0, __float_as_int(v), 0x111, 0xF, 0xF, true); v += __int_as_float(t);
  t = __builtin_amdgcn_update_dpp(0, __float_as_int(v), 0x112, 0xF, 0xF, true); v += __int_as_float(t);
  t = __builtin_amdgcn_update_dpp(0, __float_as_int(v), 0x114, 0xF, 0xF, true); v += __int_as_float(t);
  t = __builtin_amdgcn_update_dpp(0, __float_as_int(v), 0x118, 0xF, 0xF, true); v += __int_as_float(t);
  t = __builtin_amdgcn_update_dpp(0, __float_as_int(v), 0x142, 0xF, 0xF, true); v += __int_as_float(t);
  t = __builtin_amdgcn_update_dpp(0, __float_as_int(v), 0x143, 0xF, 0xF, true); v += __int_as_float(t);
  return v;
}

// ---- zero tags (every launch, replay determinism) ----
__global__ void k_init() {
  const size_t n = (size_t)16 * NN * 32;
  size_t i = (size_t)blockIdx.x * blockDim.x + threadIdx.x;
  const size_t stride = (size_t)gridDim.x * blockDim.x;
  unsigned* p = &g_T[0][0][0];
  for (; i < n; i += stride) p[i] = 0u;
}

// ---- pack Whh (all stages) and Wih (non-folded stages) to fp16 ----
__global__ void k_pack(const float* __restrict__ Wih, const float* __restrict__ Whh) {
  const size_t total = (size_t)16 * NN * NN;
  size_t i = (size_t)blockIdx.x * blockDim.x + threadIdx.x;
  const size_t stride = (size_t)gridDim.x * blockDim.x;
  for (; i < total; i += stride) {
    const int st = (int)(i >> 20);
    const int m = (int)(i >> 10) & 1023;
    const int k = (int)i & 1023;
    g_W[st][m][1024 + k] = __float2half(Whh[i]);
    const int t = st >> 1, l = st & 1;
    if (l == 1 || t == 0) g_W[st][m][k] = __float2half(Wih[i]);
  }
}

// ---- fold: W'(st=2t) = Wih[st] @ linW[t-1] ----
__global__ __launch_bounds__(256) void k_fold(const float* __restrict__ Wih,
                                              const float* __restrict__ linW) {
  const int tm1 = blockIdx.z;
  const int st = (tm1 + 1) * 2;
  const float* A = Wih + (size_t)st * NN * NN;
  const float* B = linW + (size_t)tm1 * NN * NN;
  __shared__ float sA[16][68];
  __shared__ float sB[16][68];
  const int tid = threadIdx.x;
  const int tx = tid & 15, ty = tid >> 4;
  const int bm = blockIdx.y << 6, bn = blockIdx.x << 6;
  const int lm = tid & 63, lk = (tid >> 6) << 2;
  const int rr = tid >> 4, c4 = (tid & 15) << 2;
  float acc[4][4] = {};
  for (int k0 = 0; k0 < NN; k0 += 16) {
    const float4 av = *(const float4*)&A[(size_t)(bm + lm) * NN + k0 + lk];
    const float4 bv = *(const float4*)&B[(size_t)(k0 + rr) * NN + bn + c4];
    __syncthreads();
    sA[lk + 0][lm] = av.x; sA[lk + 1][lm] = av.y; sA[lk + 2][lm] = av.z; sA[lk + 3][lm] = av.w;
    sB[rr][c4 + 0] = bv.x; sB[rr][c4 + 1] = bv.y; sB[rr][c4 + 2] = bv.z; sB[rr][c4 + 3] = bv.w;
    __syncthreads();
    #pragma unroll
    for (int kk = 0; kk < 16; ++kk) {
      const float4 a4 = *(const float4*)&sA[kk][ty << 2];
      const float4 b4 = *(const float4*)&sB[kk][tx << 2];
      const float aa[4] = {a4.x, a4.y, a4.z, a4.w};
      const float bb[4] = {b4.x, b4.y, b4.z, b4.w};
      #pragma unroll
      for (int i = 0; i < 4; ++i)
        #pragma unroll
        for (int j = 0; j < 4; ++j) acc[i][j] += aa[i] * bb[j];
    }
  }
  #pragma unroll
  for (int i = 0; i < 4; ++i)
    #pragma unroll
    for (int j = 0; j < 4; ++j)
      g_W[st][bm + (ty << 2) + i][bn + (tx << 2) + j] = __float2half(acc[i][j]);
}

// ---- combined bias per stage ----
__global__ __launch_bounds__(256) void k_bias(const float* __restrict__ Wih,
    const float* __restrict__ bih, const float* __restrict__ bhh,
    const float* __restrict__ linb) {
  const int st = blockIdx.x, t = st >> 1, l = st & 1;
  const int tid = threadIdx.x;
  __shared__ float slb[NN];
  const bool folded = (l == 0 && t > 0);
  if (folded)
    for (int k = tid; k < NN; k += 256) slb[k] = linb[(size_t)(t - 1) * NN + k];
  __syncthreads();
  for (int m = tid; m < NN; m += 256) {
    float b = bih[(size_t)st * NN + m] + bhh[(size_t)st * NN + m];
    if (folded) {
      const float* wr = Wih + (size_t)st * NN * NN + (size_t)m * NN;
      float s0 = 0, s1 = 0, s2 = 0, s3 = 0;
      for (int k = 0; k < NN; k += 4) {
        const float4 w = *(const float4*)&wr[k];
        s0 += w.x * slb[k]; s1 += w.y * slb[k + 1];
        s2 += w.z * slb[k + 2]; s3 += w.w * slb[k + 3];
      }
      b += (s0 + s1) + (s2 + s3);
    }
    g_bias[st][m] = b;
  }
}

// ---- pipelined 16-stage scan ----
// 512 WGs: stage = bid>>5, WG-in-stage = bid&31 owns rows [32wg, 32wg+32).
// Wave g owns rows 4g..4g+3; lane j owns combined cols 32j..32j+31 (in 64 VGPRs).
// Exchange: lane63 data stores (relaxed agent) -> barrier (drains vmcnt) -> tid0 tag.
// Consumers: wave0 gathers upstream x, wave1 gathers own h[s-1]; others idle at barrier.
// Deadlock-free at any residency: a WG only waits on stages <= its own, lower bids first.
__global__ __launch_bounds__(512, 4) void k_phase(const float* __restrict__ x) {
  __shared__ __align__(16) __half comb[2048];   // [x(1024) | h(1024)]
  const int tid = threadIdx.x;
  const int bid = blockIdx.x;
  const int st = bid >> 5;
  const int wg = bid & 31;
  const int woff = wg << 5;
  const int g = tid >> 6;       // wave 0..7
  const int j = tid & 63;       // lane

  // Persistent weights: rows woff+4g..+3, combined cols 32j..32j+31 (64 VGPRs).
  u32x4 w[4][4];
  #pragma unroll
  for (int r = 0; r < 4; ++r)
    #pragma unroll
    for (int k4 = 0; k4 < 4; ++k4)
      w[r][k4] = *(const u32x4*)&g_W[st][woff + 4 * g + r][32 * j + 8 * k4];
  const float4 bias = *(const float4*)&g_bias[st][woff + 4 * g];

  for (int s = 0; s < NN; ++s) {
    // ---- gather phase (waves 0 and 1 only) ----
    if (g == 0) {
      if (st == 0) {
        const float4* xp = (const float4*)&x[(size_t)s * 8192 + 16 * j];
        const float4 f0 = xp[0], f1 = xp[1], f2 = xp[2], f3 = xp[3];
        u32x4 o0, o1;
        o0.x = pk2(f0.x, f0.y); o0.y = pk2(f0.z, f0.w);
        o0.z = pk2(f1.x, f1.y); o0.w = pk2(f1.z, f1.w);
        o1.x = pk2(f2.x, f2.y); o1.y = pk2(f2.z, f2.w);
        o1.z = pk2(f3.x, f3.y); o1.w = pk2(f3.z, f3.w);
        *(u32x4*)&comb[16 * j] = o0;
        *(u32x4*)&comb[16 * j + 8] = o1;
      } else {
        while (!__hip_atomic_load(&g_T[st - 1][s][j >> 1],
                                  __ATOMIC_ACQUIRE, __HIP_MEMORY_SCOPE_AGENT))
          __builtin_amdgcn_s_sleep(1);
        #pragma unroll
        for (int i = 0; i < 4; ++i) {
          const u64 d = __hip_atomic_load(&g_D[st - 1][s][4 * j + i],
                                          __ATOMIC_RELAXED, __HIP_MEMORY_SCOPE_AGENT);
          *(u64*)&comb[16 * j + 4 * i] = d;
        }
      }
    } else if (g == 1) {
      if (s == 0) {
        #pragma unroll
        for (int i = 0; i < 4; ++i) *(u64*)&comb[1024 + 16 * j + 4 * i] = 0ull;
      } else {
        while (!__hip_atomic_load(&g_T[st][s - 1][j >> 1],
                                  __ATOMIC_ACQUIRE, __HIP_MEMORY_SCOPE_AGENT))
          __builtin_amdgcn_s_sleep(1);
        #pragma unroll
        for (int i = 0; i < 4; ++i) {
          const u64 d = __hip_atomic_load(&g_D[st][s - 1][4 * j + i],
                                          __ATOMIC_RELAXED, __HIP_MEMORY_SCOPE_AGENT);
          *(u64*)&comb[1024 + 16 * j + 4 * i] = d;
        }
      }
    }
    __syncthreads();   // B1: comb ready

    // ---- dot: 4 rows x 32 combined cols from VGPR weights ----
    const u32x4* vb = (const u32x4*)&comb[32 * j];
    float a0 = 0.f, a1 = 0.f, a2 = 0.f, a3 = 0.f;
    #pragma unroll
    for (int k4 = 0; k4 < 4; ++k4) {
      const u32x4 v = vb[k4];
      a0 = __builtin_amdgcn_fdot2(as_v2h(w[0][k4].x), as_v2h(v.x), a0, false);
      a0 = __builtin_amdgcn_fdot2(as_v2h(w[0][k4].y), as_v2h(v.y), a0, false);
      a0 = __builtin_amdgcn_fdot2(as_v2h(w[0][k4].z), as_v2h(v.z), a0, false);
      a0 = __builtin_amdgcn_fdot2(as_v2h(w[0][k4].w), as_v2h(v.w), a0, false);
      a1 = __builtin_amdgcn_fdot2(as_v2h(w[1][k4].x), as_v2h(v.x), a1, false);
      a1 = __builtin_amdgcn_fdot2(as_v2h(w[1][k4].y), as_v2h(v.y), a1, false);
      a1 = __builtin_amdgcn_fdot2(as_v2h(w[1][k4].z), as_v2h(v.z), a1, false);
      a1 = __builtin_amdgcn_fdot2(as_v2h(w[1][k4].w), as_v2h(v.w), a1, false);
      a2 = __builtin_amdgcn_fdot2(as_v2h(w[2][k4].x), as_v2h(v.x), a2, false);
      a2 = __builtin_amdgcn_fdot2(as_v2h(w[2][k4].y), as_v2h(v.y), a2, false);
      a2 = __builtin_amdgcn_fdot2(as_v2h(w[2][k4].z), as_v2h(v.z), a2, false);
      a2 = __builtin_amdgcn_fdot2(as_v2h(w[2][k4].w), as_v2h(v.w), a2, false);
      a3 = __builtin_amdgcn_fdot2(as_v2h(w[3][k4].x), as_v2h(v.x), a3, false);
      a3 = __builtin_amdgcn_fdot2(as_v2h(w[3][k4].y), as_v2h(v.y), a3, false);
      a3 = __builtin_amdgcn_fdot2(as_v2h(w[3][k4].z), as_v2h(v.z), a3, false);
      a3 = __builtin_amdgcn_fdot2(as_v2h(w[3][k4].w), as_v2h(v.w), a3, false);
    }
    a0 = dpp_reduce(a0); a1 = dpp_reduce(a1);
    a2 = dpp_reduce(a2); a3 = dpp_reduce(a3);

    if (j == 63) {
      const float h0 = tanhf(a0 + bias.x);
      const float h1 = tanhf(a1 + bias.y);
      const float h2 = tanhf(a2 + bias.z);
      const float h3 = tanhf(a3 + bias.w);
      const u64 pk = (u64)pk2(h0, h1) | ((u64)pk2(h2, h3) << 32);
      __hip_atomic_store(&g_D[st][s][8 * wg + g], pk,
                         __ATOMIC_RELAXED, __HIP_MEMORY_SCOPE_AGENT);
      if (st & 1)
        *(float4*)&g_Hout[st >> 1][(size_t)s * NN + woff + 4 * g] =
            make_float4(h0, h1, h2, h3);
    }
    __syncthreads();   // B2: drains all waves' data stores (vmcnt) before tag
    if (tid == 0)
      __hip_atomic_store(&g_T[st][s][wg], 1u,
                         __ATOMIC_RELEASE, __HIP_MEMORY_SCOPE_AGENT);
    // keep weights resident (prevent load sinking into the loop)
    asm volatile("" ::
        "v"(w[0][0]), "v"(w[0][1]), "v"(w[0][2]), "v"(w[0][3]),
        "v"(w[1][0]), "v"(w[1][1]), "v"(w[1][2]), "v"(w[1][3]),
        "v"(w[2][0]), "v"(w[2][1]), "v"(w[2][2]), "v"(w[2][3]),
        "v"(w[3][0]), "v"(w[3][1]), "v"(w[3][2]), "v"(w[3][3]));
  }
}

// ---- epilogue: out[s][t][:] = g_Hout[t][s] @ linW[t]^T + linb[t] ----
__global__ __launch_bounds__(256) void k_out(const float* __restrict__ linW,
    const float* __restrict__ linb, float* __restrict__ out) {
  const int t = blockIdx.z;
  const float* A = g_Hout[t];
  const float* B = linW + (size_t)t * NN * NN;
  __shared__ float sA[16][68];
  __shared__ float sB[16][68];
  const int tid = threadIdx.x;
  const int tx = tid & 15, ty = tid >> 4;
  const int bm = blockIdx.y << 6, bn = blockIdx.x << 6;
  const int lm = tid & 63, lk = (tid >> 6) << 2;
  float acc[4][4] = {};
  for (int k0 = 0; k0 < NN; k0 += 16) {
    const float4 av = *(const float4*)&A[(size_t)(bm + lm) * NN + k0 + lk];
    const float4 bv = *(const float4*)&B[(size_t)(bn + lm) * NN + k0 + lk];
    __syncthreads();
    sA[lk + 0][lm] = av.x; sA[lk + 1][lm] = av.y; sA[lk + 2][lm] = av.z; sA[lk + 3][lm] = av.w;
    sB[lk + 0][lm] = bv.x; sB[lk + 1][lm] = bv.y; sB[lk + 2][lm] = bv.z; sB[lk + 3][lm] = bv.w;
    __syncthreads();
    #pragma unroll
    for (int kk = 0; kk < 16; ++kk) {
      const float4 a4 = *(const float4*)&sA[kk][ty << 2];
      const float4 b4 = *(const float4*)&sB[kk][tx << 2];
      const float aa[4] = {a4.x, a4.y, a4.z, a4.w};
      const float bb[4] = {b4.x, b4.y, b4.z, b4.w};
      #pragma unroll
      for (int i = 0; i < 4; ++i)
        #pragma unroll
        for (int j = 0; j < 4; ++j) acc[i][j] += aa[i] * bb[j];
    }
  }
  const int n0 = bn + (tx << 2);
  float bias[4];
  #pragma unroll
  for (int j = 0; j < 4; ++j) bias[j] = linb[(size_t)t * NN + n0 + j];
  #pragma unroll
  for (int i = 0; i < 4; ++i) {
    const int m = bm + (ty << 2) + i;
    float4 o;
    o.x = acc[i][0] + bias[0]; o.y = acc[i][1] + bias[1];
    o.z = acc[i][2] + bias[2]; o.w = acc[i][3] + bias[3];
    *(float4*)&out[(size_t)m * 8192 + (size_t)t * NN + n0] = o;
  }
}

extern "C" void kernel_launch(void* const* d_in, const int* in_sizes, int n_in,
                              void* d_out, int out_size, void* d_ws, size_t ws_size,
                              hipStream_t stream) {
  (void)in_sizes; (void)n_in; (void)out_size; (void)d_ws; (void)ws_size;
  const float* x    = (const float*)d_in[0];
  const float* Wih  = (const float*)d_in[1];
  const float* Whh  = (const float*)d_in[2];
  const float* bih  = (const float*)d_in[3];
  const float* bhh  = (const float*)d_in[4];
  const float* linW = (const float*)d_in[5];
  const float* linb = (const float*)d_in[6];
  float* out = (float*)d_out;

  k_init<<<256, 256, 0, stream>>>();
  k_pack<<<2048, 256, 0, stream>>>(Wih, Whh);
  k_fold<<<dim3(16, 16, 7), 256, 0, stream>>>(Wih, linW);
  k_bias<<<16, 256, 0, stream>>>(Wih, bih, bhh, linb);
  k_phase<<<512, 512, 0, stream>>>(x);
  k_out<<<dim3(16, 16, 8), 256, 0, stream>>>(linW, linb, out);
}

// Round 6
// 6779.779 us; speedup vs baseline: 3.3258x; 3.3258x over previous
//
#include <hip/hip_runtime.h>
#include <hip/hip_fp16.h>

#define NN 1024
#define ROWS 16                 // output rows per WG
#define WPS 64                  // WGs per stage
#define NST 16                  // stages
#define RS_H 2072               // LDS weight row stride in halves (259 16B-units, odd -> uniform bank groups)
#define SM_W (ROWS * RS_H * 2)  // 66304 B weights
#define SM_COMB (2048 * 2)      // 4096 B combined vector [x | h]
#define SM_SPW (8 * 16 * 4)     // 512 B wave partials
#define SM_TOTAL (SM_W + SM_COMB + SM_SPW)   // 70912 B -> 2 WG/CU

typedef _Float16 v2h __attribute__((ext_vector_type(2)));
typedef unsigned int uint;
typedef unsigned long long u64;
typedef unsigned int u32x4 __attribute__((ext_vector_type(4)));

// Static device scratch.
__device__ __half g_W[NST][NN][2048];      // per stage row: [Wih_eff(1024) | Whh(1024)] fp16
__device__ float g_bias[NST][NN];          // combined bias fp32
__device__ u64 g_S[NST][NN][512];          // {1<<32 | fp16 h[2q+1],h[2q]}; full per-step storage
__device__ float g_Hout[8][NN * NN];       // h of odd stages (pre-linear), fp32

__device__ __forceinline__ v2h as_v2h(uint u) {
  union { uint u; v2h h; } c; c.u = u; return c.h;
}
__device__ __forceinline__ uint pk2(float a, float b) {
  union { v2h h; uint u; } c; c.h.x = (_Float16)a; c.h.y = (_Float16)b; return c.u;
}
// 16B-unit rotation swizzle for the shared vector (spreads bank groups).
__device__ __forceinline__ int vswz_byte(int logical_byte) {
  const int u = logical_byte >> 4;
  const int pu = (u & ~7) | ((u + (u >> 3)) & 7);
  return (pu << 4) | (logical_byte & 15);
}

// ---- zero exchange slots (every launch, replay determinism) ----
__global__ void k_init() {
  const size_t n = (size_t)NST * NN * 512;
  size_t i = (size_t)blockIdx.x * blockDim.x + threadIdx.x;
  const size_t stride = (size_t)gridDim.x * blockDim.x;
  u64* p = &g_S[0][0][0];
  for (; i < n; i += stride) p[i] = 0ull;
}

// ---- pack Whh (all stages) and Wih (non-folded stages) to fp16 ----
__global__ void k_pack(const float* __restrict__ Wih, const float* __restrict__ Whh) {
  const size_t total = (size_t)NST * NN * NN;
  size_t i = (size_t)blockIdx.x * blockDim.x + threadIdx.x;
  const size_t stride = (size_t)gridDim.x * blockDim.x;
  for (; i < total; i += stride) {
    const int st = (int)(i >> 20);
    const int m = (int)(i >> 10) & 1023;
    const int k = (int)i & 1023;
    g_W[st][m][1024 + k] = __float2half(Whh[i]);
    const int t = st >> 1, l = st & 1;
    if (l == 1 || t == 0) g_W[st][m][k] = __float2half(Wih[i]);
  }
}

// ---- fold: W'(st=2t) = Wih[st] @ linW[t-1] ----
__global__ __launch_bounds__(256) void k_fold(const float* __restrict__ Wih,
                                              const float* __restrict__ linW) {
  const int tm1 = blockIdx.z;
  const int st = (tm1 + 1) * 2;
  const float* A = Wih + (size_t)st * NN * NN;
  const float* B = linW + (size_t)tm1 * NN * NN;
  __shared__ float sA[16][68];
  __shared__ float sB[16][68];
  const int tid = threadIdx.x;
  const int tx = tid & 15, ty = tid >> 4;
  const int bm = blockIdx.y << 6, bn = blockIdx.x << 6;
  const int lm = tid & 63, lk = (tid >> 6) << 2;
  const int rr = tid >> 4, c4 = (tid & 15) << 2;
  float acc[4][4] = {};
  for (int k0 = 0; k0 < NN; k0 += 16) {
    const float4 av = *(const float4*)&A[(size_t)(bm + lm) * NN + k0 + lk];
    const float4 bv = *(const float4*)&B[(size_t)(k0 + rr) * NN + bn + c4];
    __syncthreads();
    sA[lk + 0][lm] = av.x; sA[lk + 1][lm] = av.y; sA[lk + 2][lm] = av.z; sA[lk + 3][lm] = av.w;
    sB[rr][c4 + 0] = bv.x; sB[rr][c4 + 1] = bv.y; sB[rr][c4 + 2] = bv.z; sB[rr][c4 + 3] = bv.w;
    __syncthreads();
    #pragma unroll
    for (int kk = 0; kk < 16; ++kk) {
      const float4 a4 = *(const float4*)&sA[kk][ty << 2];
      const float4 b4 = *(const float4*)&sB[kk][tx << 2];
      const float aa[4] = {a4.x, a4.y, a4.z, a4.w};
      const float bb[4] = {b4.x, b4.y, b4.z, b4.w};
      #pragma unroll
      for (int i = 0; i < 4; ++i)
        #pragma unroll
        for (int j = 0; j < 4; ++j) acc[i][j] += aa[i] * bb[j];
    }
  }
  #pragma unroll
  for (int i = 0; i < 4; ++i)
    #pragma unroll
    for (int j = 0; j < 4; ++j)
      g_W[st][bm + (ty << 2) + i][bn + (tx << 2) + j] = __float2half(acc[i][j]);
}

// ---- combined bias per stage ----
__global__ __launch_bounds__(256) void k_bias(const float* __restrict__ Wih,
    const float* __restrict__ bih, const float* __restrict__ bhh,
    const float* __restrict__ linb) {
  const int st = blockIdx.x, t = st >> 1, l = st & 1;
  const int tid = threadIdx.x;
  __shared__ float slb[NN];
  const bool folded = (l == 0 && t > 0);
  if (folded)
    for (int k = tid; k < NN; k += 256) slb[k] = linb[(size_t)(t - 1) * NN + k];
  __syncthreads();
  for (int m = tid; m < NN; m += 256) {
    float b = bih[(size_t)st * NN + m] + bhh[(size_t)st * NN + m];
    if (folded) {
      const float* wr = Wih + (size_t)st * NN * NN + (size_t)m * NN;
      float s0 = 0, s1 = 0, s2 = 0, s3 = 0;
      for (int k = 0; k < NN; k += 4) {
        const float4 w = *(const float4*)&wr[k];
        s0 += w.x * slb[k]; s1 += w.y * slb[k + 1];
        s2 += w.z * slb[k + 2]; s3 += w.w * slb[k + 3];
      }
      b += (s0 + s1) + (s2 + s3);
    }
    g_bias[st][m] = b;
  }
}

// ---- pipelined 16-stage scan, one dispatch ----
// bid: stage = bid>>6, wg = bid&63 owns rows [16wg, 16wg+16).
// Thread (r=tid&15, c=tid>>4): row woff+r, combined-col chunk c (64 halves).
// Exchange: relaxed agent u64 {tag,2xfp16} data-in-slot; every thread polls 1 own + 1 upstream slot.
// Deadlock-free: WG waits only on same/earlier stages; blocks place in bid order; retirement frees slots.
__global__ __launch_bounds__(512, 4) void k_phase(const float* __restrict__ x) {
  extern __shared__ __align__(16) unsigned char smem[];
  __half* sW = (__half*)smem;                         // [ROWS][RS_H]
  unsigned char* combB = smem + SM_W;                 // [4096] bytes, unit-swizzled [x|h]
  float* spw = (float*)(smem + SM_W + SM_COMB);       // [8][16]
  const int tid = threadIdx.x;
  const int bid = blockIdx.x;
  const int st = bid >> 6;
  const int wg = bid & 63;
  const int woff = wg << 4;
  const int r = tid & 15;
  const int c = tid >> 4;       // 0..31
  const int g = tid >> 6;       // wave

  // Stage weights into LDS: 16 rows x 256 16B-units (full 2048 halves/row).
  for (int idx = tid; idx < ROWS * 256; idx += 512) {
    const int m = idx >> 8, u = idx & 255;
    const u32x4 v = *(const u32x4*)&g_W[st][woff + m][u * 8];
    *(u32x4*)&sW[m * RS_H + u * 8] = v;
  }
  float breg = 0.f;
  if (tid < 16) breg = g_bias[st][woff + tid];

  // Swizzled byte offsets for this thread's comb writes (x-part byte 0.., h-part byte 2048..).
  const int wbx = vswz_byte(4 * tid);
  const int wbh = vswz_byte(2048 + 4 * tid);

  float2 xr;
  if (st == 0) xr = *(const float2*)&x[2 * tid];

  for (int s = 0; s < NN; ++s) {
    // ---- gather: every thread resolves 1 upstream + 1 own slot ----
    uint xu = 0, hu = 0;
    bool needU = (st > 0);
    bool needO = (s > 0);
    if (st == 0) xu = pk2(xr.x, xr.y);
    if (needU || needO) {
      const u64* pu = needU ? &g_S[st - 1][s][tid] : nullptr;
      const u64* po = needO ? &g_S[st][s - 1][tid] : nullptr;
      while (needU || needO) {
        u64 a = 0, b = 0;
        if (needU) a = __hip_atomic_load(pu, __ATOMIC_RELAXED, __HIP_MEMORY_SCOPE_AGENT);
        if (needO) b = __hip_atomic_load(po, __ATOMIC_RELAXED, __HIP_MEMORY_SCOPE_AGENT);
        if (needU && (a >> 32)) { xu = (uint)a; needU = false; }
        if (needO && (b >> 32)) { hu = (uint)b; needO = false; }
        if (needU || needO) __builtin_amdgcn_s_sleep(1);
      }
    }
    *(uint*)&combB[wbx] = xu;
    *(uint*)&combB[wbh] = hu;
    if (st == 0 && s + 1 < NN) xr = *(const float2*)&x[(size_t)(s + 1) * 8192 + 2 * tid];
    __syncthreads();   // B1: comb + (first iter) sW ready

    // ---- dot: row r, combined cols [64c, 64c+64) ----
    const __half* wr = &sW[r * RS_H + c * 64];
    float a0 = 0.f, a1 = 0.f;
    #pragma unroll
    for (int i = 0; i < 8; ++i) {
      const u32x4 w = *(const u32x4*)&wr[8 * i];
      const u32x4 v = *(const u32x4*)&combB[vswz_byte((c * 64 + 8 * i) * 2)];
      a0 = __builtin_amdgcn_fdot2(as_v2h(w.x), as_v2h(v.x), a0, false);
      a1 = __builtin_amdgcn_fdot2(as_v2h(w.y), as_v2h(v.y), a1, false);
      a0 = __builtin_amdgcn_fdot2(as_v2h(w.z), as_v2h(v.z), a0, false);
      a1 = __builtin_amdgcn_fdot2(as_v2h(w.w), as_v2h(v.w), a1, false);
    }
    float acc = a0 + a1;
    acc += __shfl_xor(acc, 16);
    acc += __shfl_xor(acc, 32);          // lanes with same r hold wave sum
    if ((tid & 63) < 16) spw[g * 16 + r] = acc;
    __syncthreads();   // B2: spw ready; all comb reads done

    // ---- finish: wave 0 lanes 0..15 ----
    if (tid < 16) {
      float dot = breg;
      #pragma unroll
      for (int k = 0; k < 8; ++k) dot += spw[k * 16 + tid];
      const float hv = tanhf(dot);
      const float hp = __shfl_xor(hv, 1);
      if ((tid & 1) == 0) {
        const u64 pv = (1ull << 32) | (u64)pk2(hv, hp);
        __hip_atomic_store(&g_S[st][s][wg * 8 + (tid >> 1)], pv,
                           __ATOMIC_RELAXED, __HIP_MEMORY_SCOPE_AGENT);
      }
      if (st & 1) g_Hout[st >> 1][(size_t)s * NN + woff + tid] = hv;
    }
    // no extra barrier: gather(s+1) writes comb only before B1(s+1)
  }
}

// ---- epilogue: out[s][t][:] = g_Hout[t][s] @ linW[t]^T + linb[t] ----
__global__ __launch_bounds__(256) void k_out(const float* __restrict__ linW,
    const float* __restrict__ linb, float* __restrict__ out) {
  const int t = blockIdx.z;
  const float* A = g_Hout[t];
  const float* B = linW + (size_t)t * NN * NN;
  __shared__ float sA[16][68];
  __shared__ float sB[16][68];
  const int tid = threadIdx.x;
  const int tx = tid & 15, ty = tid >> 4;
  const int bm = blockIdx.y << 6, bn = blockIdx.x << 6;
  const int lm = tid & 63, lk = (tid >> 6) << 2;
  float acc[4][4] = {};
  for (int k0 = 0; k0 < NN; k0 += 16) {
    const float4 av = *(const float4*)&A[(size_t)(bm + lm) * NN + k0 + lk];
    const float4 bv = *(const float4*)&B[(size_t)(bn + lm) * NN + k0 + lk];
    __syncthreads();
    sA[lk + 0][lm] = av.x; sA[lk + 1][lm] = av.y; sA[lk + 2][lm] = av.z; sA[lk + 3][lm] = av.w;
    sB[lk + 0][lm] = bv.x; sB[lk + 1][lm] = bv.y; sB[lk + 2][lm] = bv.z; sB[lk + 3][lm] = bv.w;
    __syncthreads();
    #pragma unroll
    for (int kk = 0; kk < 16; ++kk) {
      const float4 a4 = *(const float4*)&sA[kk][ty << 2];
      const float4 b4 = *(const float4*)&sB[kk][tx << 2];
      const float aa[4] = {a4.x, a4.y, a4.z, a4.w};
      const float bb[4] = {b4.x, b4.y, b4.z, b4.w};
      #pragma unroll
      for (int i = 0; i < 4; ++i)
        #pragma unroll
        for (int j = 0; j < 4; ++j) acc[i][j] += aa[i] * bb[j];
    }
  }
  const int n0 = bn + (tx << 2);
  float bias[4];
  #pragma unroll
  for (int j = 0; j < 4; ++j) bias[j] = linb[(size_t)t * NN + n0 + j];
  #pragma unroll
  for (int i = 0; i < 4; ++i) {
    const int m = bm + (ty << 2) + i;
    float4 o;
    o.x = acc[i][0] + bias[0]; o.y = acc[i][1] + bias[1];
    o.z = acc[i][2] + bias[2]; o.w = acc[i][3] + bias[3];
    *(float4*)&out[(size_t)m * 8192 + (size_t)t * NN + n0] = o;
  }
}

extern "C" void kernel_launch(void* const* d_in, const int* in_sizes, int n_in,
                              void* d_out, int out_size, void* d_ws, size_t ws_size,
                              hipStream_t stream) {
  (void)in_sizes; (void)n_in; (void)out_size; (void)d_ws; (void)ws_size;
  const float* x    = (const float*)d_in[0];
  const float* Wih  = (const float*)d_in[1];
  const float* Whh  = (const float*)d_in[2];
  const float* bih  = (const float*)d_in[3];
  const float* bhh  = (const float*)d_in[4];
  const float* linW = (const float*)d_in[5];
  const float* linb = (const float*)d_in[6];
  float* out = (float*)d_out;

  (void)hipFuncSetAttribute((const void*)k_phase,
                            hipFuncAttributeMaxDynamicSharedMemorySize, SM_TOTAL);

  k_init<<<2048, 256, 0, stream>>>();
  k_pack<<<2048, 256, 0, stream>>>(Wih, Whh);
  k_fold<<<dim3(16, 16, 7), 256, 0, stream>>>(Wih, linW);
  k_bias<<<16, 256, 0, stream>>>(Wih, bih, bhh, linb);
  k_phase<<<NST * WPS, 512, SM_TOTAL, stream>>>(x);
  k_out<<<dim3(16, 16, 8), 256, 0, stream>>>(linW, linb, out);
}

// Round 7
// 4655.807 us; speedup vs baseline: 4.8431x; 1.4562x over previous
//
#include <hip/hip_runtime.h>
#include <hip/hip_fp16.h>

#define NN 1024
#define NST 16
#define WPS 32                  // WGs per stage
#define ROWS 32                 // rows per WG

typedef _Float16 v2h __attribute__((ext_vector_type(2)));
typedef unsigned int uint;
typedef unsigned long long u64;
typedef unsigned int u32x4 __attribute__((ext_vector_type(4)));

// Static device scratch.
__device__ __half g_W[NST][NN][2048];      // per stage row: [Wih_eff(1024) | Whh(1024)] fp16
__device__ float g_bias[NST][NN];          // combined bias fp32
__device__ u64 g_S[NST][NN][512];          // slot q = {1<<32 | fp16 h[2q+1],h[2q]}
__device__ float g_Hout[8][NN * NN];       // h of odd stages (pre-linear), fp32

__device__ __forceinline__ v2h as_v2h(uint u) {
  union { uint u; v2h h; } c; c.u = u; return c.h;
}
__device__ __forceinline__ uint pk2(float a, float b) {
  union { v2h h; uint u; } c; c.h.x = (_Float16)a; c.h.y = (_Float16)b; return c.u;
}
// 16B-unit rotation swizzle (permutes units within 8-unit blocks -> spreads bank groups).
__device__ __forceinline__ int vswz_byte(int logical_byte) {
  const int u = logical_byte >> 4;
  const int pu = (u & ~7) | ((u + (u >> 3)) & 7);
  return (pu << 4) | (logical_byte & 15);
}

// ---- zero exchange slots (every launch, replay determinism) ----
__global__ void k_init() {
  const size_t n = (size_t)NST * NN * 512;
  size_t i = (size_t)blockIdx.x * blockDim.x + threadIdx.x;
  const size_t stride = (size_t)gridDim.x * blockDim.x;
  u64* p = &g_S[0][0][0];
  for (; i < n; i += stride) p[i] = 0ull;
}

// ---- pack Whh (all stages) and Wih (non-folded stages) to fp16 ----
__global__ void k_pack(const float* __restrict__ Wih, const float* __restrict__ Whh) {
  const size_t total = (size_t)NST * NN * NN;
  size_t i = (size_t)blockIdx.x * blockDim.x + threadIdx.x;
  const size_t stride = (size_t)gridDim.x * blockDim.x;
  for (; i < total; i += stride) {
    const int st = (int)(i >> 20);
    const int m = (int)(i >> 10) & 1023;
    const int k = (int)i & 1023;
    g_W[st][m][1024 + k] = __float2half(Whh[i]);
    const int t = st >> 1, l = st & 1;
    if (l == 1 || t == 0) g_W[st][m][k] = __float2half(Wih[i]);
  }
}

// ---- fold: W'(st=2t) = Wih[st] @ linW[t-1] ----
__global__ __launch_bounds__(256) void k_fold(const float* __restrict__ Wih,
                                              const float* __restrict__ linW) {
  const int tm1 = blockIdx.z;
  const int st = (tm1 + 1) * 2;
  const float* A = Wih + (size_t)st * NN * NN;
  const float* B = linW + (size_t)tm1 * NN * NN;
  __shared__ float sA[16][68];
  __shared__ float sB[16][68];
  const int tid = threadIdx.x;
  const int tx = tid & 15, ty = tid >> 4;
  const int bm = blockIdx.y << 6, bn = blockIdx.x << 6;
  const int lm = tid & 63, lk = (tid >> 6) << 2;
  const int rr = tid >> 4, c4 = (tid & 15) << 2;
  float acc[4][4] = {};
  for (int k0 = 0; k0 < NN; k0 += 16) {
    const float4 av = *(const float4*)&A[(size_t)(bm + lm) * NN + k0 + lk];
    const float4 bv = *(const float4*)&B[(size_t)(k0 + rr) * NN + bn + c4];
    __syncthreads();
    sA[lk + 0][lm] = av.x; sA[lk + 1][lm] = av.y; sA[lk + 2][lm] = av.z; sA[lk + 3][lm] = av.w;
    sB[rr][c4 + 0] = bv.x; sB[rr][c4 + 1] = bv.y; sB[rr][c4 + 2] = bv.z; sB[rr][c4 + 3] = bv.w;
    __syncthreads();
    #pragma unroll
    for (int kk = 0; kk < 16; ++kk) {
      const float4 a4 = *(const float4*)&sA[kk][ty << 2];
      const float4 b4 = *(const float4*)&sB[kk][tx << 2];
      const float aa[4] = {a4.x, a4.y, a4.z, a4.w};
      const float bb[4] = {b4.x, b4.y, b4.z, b4.w};
      #pragma unroll
      for (int i = 0; i < 4; ++i)
        #pragma unroll
        for (int j = 0; j < 4; ++j) acc[i][j] += aa[i] * bb[j];
    }
  }
  #pragma unroll
  for (int i = 0; i < 4; ++i)
    #pragma unroll
    for (int j = 0; j < 4; ++j)
      g_W[st][bm + (ty << 2) + i][bn + (tx << 2) + j] = __float2half(acc[i][j]);
}

// ---- combined bias per stage ----
__global__ __launch_bounds__(256) void k_bias(const float* __restrict__ Wih,
    const float* __restrict__ bih, const float* __restrict__ bhh,
    const float* __restrict__ linb) {
  const int st = blockIdx.x, t = st >> 1, l = st & 1;
  const int tid = threadIdx.x;
  __shared__ float slb[NN];
  const bool folded = (l == 0 && t > 0);
  if (folded)
    for (int k = tid; k < NN; k += 256) slb[k] = linb[(size_t)(t - 1) * NN + k];
  __syncthreads();
  for (int m = tid; m < NN; m += 256) {
    float b = bih[(size_t)st * NN + m] + bhh[(size_t)st * NN + m];
    if (folded) {
      const float* wr = Wih + (size_t)st * NN * NN + (size_t)m * NN;
      float s0 = 0, s1 = 0, s2 = 0, s3 = 0;
      for (int k = 0; k < NN; k += 4) {
        const float4 w = *(const float4*)&wr[k];
        s0 += w.x * slb[k]; s1 += w.y * slb[k + 1];
        s2 += w.z * slb[k + 2]; s3 += w.w * slb[k + 3];
      }
      b += (s0 + s1) + (s2 + s3);
    }
    g_bias[st][m] = b;
  }
}

// ---- pipelined 16-stage scan, one dispatch, weights in VGPRs ----
// 512 WGs x 256 thr, __launch_bounds__(256,2): all WGs resident (2 WG/CU guaranteed).
// bid: stage = bid>>5, wg = bid&31 owns rows [32wg, 32wg+32).
// Lane (a=tid&7, c=tid>>3): rows woff+4a..+3, combined cols [64c,64c+64) -> 128 weight VGPRs.
// Gather: waves 0-1 poll own h(s-1) (4 slots/lane), waves 2-3 poll upstream / load x.
// Exchange: relaxed agent u64 {tag, 2xfp16} data-in-slot (single L3 round trip).
__global__ __launch_bounds__(256, 2) void k_phase(const float* __restrict__ x) {
  __shared__ __align__(16) unsigned char comb[4096];   // units 0..127 = X, 128..255 = H (vswz'd)
  __shared__ float spwf[32 * 33];
  const int tid = threadIdx.x;
  const int bid = blockIdx.x;
  const int st = bid >> 5;
  const int wg = bid & 31;
  const int woff = wg << 5;
  const int wid = tid >> 6;
  const int lane = tid & 63;
  const int a = tid & 7;
  const int c = tid >> 3;      // 0..31

  // Persistent weights: 4 rows x 64 cols = 32 u32x4 = 128 VGPRs.
  u32x4 w[4][8];
  #pragma unroll
  for (int r = 0; r < 4; ++r)
    #pragma unroll
    for (int i = 0; i < 8; ++i)
      w[r][i] = *(const u32x4*)&g_W[st][woff + 4 * a + r][64 * c + 8 * i];
  float breg = 0.f;
  if (tid < 32) breg = g_bias[st][woff + tid];

  for (int s = 0; s < NN; ++s) {
    // ---------- gather ----------
    if (wid < 2) {
      // own h(s-1): 128 lanes x 4 slots -> H units 128+pl
      const int pl = wid * 64 + lane;
      const int pb = vswz_byte((128 + pl) * 16);
      if (s == 0) {
        *(u32x4*)&comb[pb] = (u32x4){0u, 0u, 0u, 0u};
      } else {
        const u64* sp = &g_S[st][s - 1][4 * pl];
        uint done = 0;
        while (done != 0xFu) {
          #pragma unroll
          for (int i = 0; i < 4; ++i)
            if (!(done & (1u << i))) {
              const u64 v = __hip_atomic_load(&sp[i], __ATOMIC_RELAXED, __HIP_MEMORY_SCOPE_AGENT);
              if (v >> 32) { *(uint*)&comb[pb + 4 * i] = (uint)v; done |= 1u << i; }
            }
          if (done != 0xFu) __builtin_amdgcn_s_sleep(1);
        }
      }
    } else {
      // upstream h(s) or x(s): 128 lanes -> X units pl
      const int pl = (wid - 2) * 64 + lane;
      const int pb = vswz_byte(pl * 16);
      if (st == 0) {
        const float4 f0 = *(const float4*)&x[(size_t)s * 8192 + 8 * pl];
        const float4 f1 = *(const float4*)&x[(size_t)s * 8192 + 8 * pl + 4];
        u32x4 o;
        o.x = pk2(f0.x, f0.y); o.y = pk2(f0.z, f0.w);
        o.z = pk2(f1.x, f1.y); o.w = pk2(f1.z, f1.w);
        *(u32x4*)&comb[pb] = o;
      } else {
        const u64* sp = &g_S[st - 1][s][4 * pl];
        uint done = 0;
        while (done != 0xFu) {
          #pragma unroll
          for (int i = 0; i < 4; ++i)
            if (!(done & (1u << i))) {
              const u64 v = __hip_atomic_load(&sp[i], __ATOMIC_RELAXED, __HIP_MEMORY_SCOPE_AGENT);
              if (v >> 32) { *(uint*)&comb[pb + 4 * i] = (uint)v; done |= 1u << i; }
            }
          if (done != 0xFu) __builtin_amdgcn_s_sleep(1);
        }
      }
    }
    __syncthreads();   // B1: comb ready

    // ---------- dot: 4 rows x 64 combined cols from VGPR weights ----------
    float p0 = 0.f, p1 = 0.f, p2 = 0.f, p3 = 0.f;
    #pragma unroll
    for (int i = 0; i < 8; ++i) {
      const u32x4 v = *(const u32x4*)&comb[vswz_byte((8 * c + i) * 16)];
      p0 = __builtin_amdgcn_fdot2(as_v2h(w[0][i].x), as_v2h(v.x), p0, false);
      p0 = __builtin_amdgcn_fdot2(as_v2h(w[0][i].y), as_v2h(v.y), p0, false);
      p0 = __builtin_amdgcn_fdot2(as_v2h(w[0][i].z), as_v2h(v.z), p0, false);
      p0 = __builtin_amdgcn_fdot2(as_v2h(w[0][i].w), as_v2h(v.w), p0, false);
      p1 = __builtin_amdgcn_fdot2(as_v2h(w[1][i].x), as_v2h(v.x), p1, false);
      p1 = __builtin_amdgcn_fdot2(as_v2h(w[1][i].y), as_v2h(v.y), p1, false);
      p1 = __builtin_amdgcn_fdot2(as_v2h(w[1][i].z), as_v2h(v.z), p1, false);
      p1 = __builtin_amdgcn_fdot2(as_v2h(w[1][i].w), as_v2h(v.w), p1, false);
      p2 = __builtin_amdgcn_fdot2(as_v2h(w[2][i].x), as_v2h(v.x), p2, false);
      p2 = __builtin_amdgcn_fdot2(as_v2h(w[2][i].y), as_v2h(v.y), p2, false);
      p2 = __builtin_amdgcn_fdot2(as_v2h(w[2][i].z), as_v2h(v.z), p2, false);
      p2 = __builtin_amdgcn_fdot2(as_v2h(w[2][i].w), as_v2h(v.w), p2, false);
      p3 = __builtin_amdgcn_fdot2(as_v2h(w[3][i].x), as_v2h(v.x), p3, false);
      p3 = __builtin_amdgcn_fdot2(as_v2h(w[3][i].y), as_v2h(v.y), p3, false);
      p3 = __builtin_amdgcn_fdot2(as_v2h(w[3][i].z), as_v2h(v.z), p3, false);
      p3 = __builtin_amdgcn_fdot2(as_v2h(w[3][i].w), as_v2h(v.w), p3, false);
    }
    spwf[c * 33 + 4 * a + 0] = p0;
    spwf[c * 33 + 4 * a + 1] = p1;
    spwf[c * 33 + 4 * a + 2] = p2;
    spwf[c * 33 + 4 * a + 3] = p3;
    __syncthreads();   // B2: spw ready

    // ---------- finish: wave 0 lanes 0..31 ----------
    if (tid < 32) {
      float dot = breg;
      #pragma unroll
      for (int cc = 0; cc < 32; ++cc) dot += spwf[cc * 33 + tid];
      const float hv = tanhf(dot);
      const float hp = __shfl_down(hv, 1);
      if ((tid & 1) == 0) {
        const u64 pv = (1ull << 32) | (u64)pk2(hv, hp);
        __hip_atomic_store(&g_S[st][s][wg * 16 + (tid >> 1)], pv,
                           __ATOMIC_RELAXED, __HIP_MEMORY_SCOPE_AGENT);
      }
      if (st & 1) g_Hout[st >> 1][(size_t)s * NN + woff + tid] = hv;
    }
    // keep weights resident
    asm volatile("" ::
        "v"(w[0][0]), "v"(w[0][1]), "v"(w[0][2]), "v"(w[0][3]),
        "v"(w[0][4]), "v"(w[0][5]), "v"(w[0][6]), "v"(w[0][7]),
        "v"(w[1][0]), "v"(w[1][1]), "v"(w[1][2]), "v"(w[1][3]),
        "v"(w[1][4]), "v"(w[1][5]), "v"(w[1][6]), "v"(w[1][7]),
        "v"(w[2][0]), "v"(w[2][1]), "v"(w[2][2]), "v"(w[2][3]),
        "v"(w[2][4]), "v"(w[2][5]), "v"(w[2][6]), "v"(w[2][7]),
        "v"(w[3][0]), "v"(w[3][1]), "v"(w[3][2]), "v"(w[3][3]),
        "v"(w[3][4]), "v"(w[3][5]), "v"(w[3][6]), "v"(w[3][7]));
    // no trailing barrier: next gather writes comb only before B1(s+1)
  }
}

// ---- epilogue: out[s][t][:] = g_Hout[t][s] @ linW[t]^T + linb[t] ----
__global__ __launch_bounds__(256) void k_out(const float* __restrict__ linW,
    const float* __restrict__ linb, float* __restrict__ out) {
  const int t = blockIdx.z;
  const float* A = g_Hout[t];
  const float* B = linW + (size_t)t * NN * NN;
  __shared__ float sA[16][68];
  __shared__ float sB[16][68];
  const int tid = threadIdx.x;
  const int tx = tid & 15, ty = tid >> 4;
  const int bm = blockIdx.y << 6, bn = blockIdx.x << 6;
  const int lm = tid & 63, lk = (tid >> 6) << 2;
  float acc[4][4] = {};
  for (int k0 = 0; k0 < NN; k0 += 16) {
    const float4 av = *(const float4*)&A[(size_t)(bm + lm) * NN + k0 + lk];
    const float4 bv = *(const float4*)&B[(size_t)(bn + lm) * NN + k0 + lk];
    __syncthreads();
    sA[lk + 0][lm] = av.x; sA[lk + 1][lm] = av.y; sA[lk + 2][lm] = av.z; sA[lk + 3][lm] = av.w;
    sB[lk + 0][lm] = bv.x; sB[lk + 1][lm] = bv.y; sB[lk + 2][lm] = bv.z; sB[lk + 3][lm] = bv.w;
    __syncthreads();
    #pragma unroll
    for (int kk = 0; kk < 16; ++kk) {
      const float4 a4 = *(const float4*)&sA[kk][ty << 2];
      const float4 b4 = *(const float4*)&sB[kk][tx << 2];
      const float aa[4] = {a4.x, a4.y, a4.z, a4.w};
      const float bb[4] = {b4.x, b4.y, b4.z, b4.w};
      #pragma unroll
      for (int i = 0; i < 4; ++i)
        #pragma unroll
        for (int j = 0; j < 4; ++j) acc[i][j] += aa[i] * bb[j];
    }
  }
  const int n0 = bn + (tx << 2);
  float bias[4];
  #pragma unroll
  for (int j = 0; j < 4; ++j) bias[j] = linb[(size_t)t * NN + n0 + j];
  #pragma unroll
  for (int i = 0; i < 4; ++i) {
    const int m = bm + (ty << 2) + i;
    float4 o;
    o.x = acc[i][0] + bias[0]; o.y = acc[i][1] + bias[1];
    o.z = acc[i][2] + bias[2]; o.w = acc[i][3] + bias[3];
    *(float4*)&out[(size_t)m * 8192 + (size_t)t * NN + n0] = o;
  }
}

extern "C" void kernel_launch(void* const* d_in, const int* in_sizes, int n_in,
                              void* d_out, int out_size, void* d_ws, size_t ws_size,
                              hipStream_t stream) {
  (void)in_sizes; (void)n_in; (void)out_size; (void)d_ws; (void)ws_size;
  const float* x    = (const float*)d_in[0];
  const float* Wih  = (const float*)d_in[1];
  const float* Whh  = (const float*)d_in[2];
  const float* bih  = (const float*)d_in[3];
  const float* bhh  = (const float*)d_in[4];
  const float* linW = (const float*)d_in[5];
  const float* linb = (const float*)d_in[6];
  float* out = (float*)d_out;

  k_init<<<2048, 256, 0, stream>>>();
  k_pack<<<2048, 256, 0, stream>>>(Wih, Whh);
  k_fold<<<dim3(16, 16, 7), 256, 0, stream>>>(Wih, linW);
  k_bias<<<16, 256, 0, stream>>>(Wih, bih, bhh, linb);
  k_phase<<<NST * WPS, 256, 0, stream>>>(x);
  k_out<<<dim3(16, 16, 8), 256, 0, stream>>>(linW, linb, out);
}

// Round 8
// 4376.146 us; speedup vs baseline: 5.1526x; 1.0639x over previous
//
#include <hip/hip_runtime.h>
#include <hip/hip_fp16.h>

#define NN 1024
#define NST 16
#define WPS 32                  // WGs per stage
#define ROWS 32                 // rows per WG

typedef _Float16 v2h __attribute__((ext_vector_type(2)));
typedef unsigned int uint;
typedef unsigned long long u64;
typedef unsigned int u32x4 __attribute__((ext_vector_type(4)));

// Static device scratch.
__device__ __half g_W[NST][NN][2048];      // per stage row: [Wih_eff(1024) | Whh(1024)] fp16
__device__ float g_bias[NST][NN];          // combined bias fp32
__device__ u64 g_S[NST][NN][512];          // slot q = {1<<32 | fp16 h[2q+1],h[2q]}
__device__ float g_Hout[8][NN * NN];       // h of odd stages (pre-linear), fp32

__device__ __forceinline__ v2h as_v2h(uint u) {
  union { uint u; v2h h; } c; c.u = u; return c.h;
}
__device__ __forceinline__ uint pk2(float a, float b) {
  union { v2h h; uint u; } c; c.h.x = (_Float16)a; c.h.y = (_Float16)b; return c.u;
}
// 16B-unit rotation swizzle (permutes units within 8-unit blocks -> spreads bank groups).
__device__ __forceinline__ int vswz_byte(int logical_byte) {
  const int u = logical_byte >> 4;
  const int pu = (u & ~7) | ((u + (u >> 3)) & 7);
  return (pu << 4) | (logical_byte & 15);
}
// Opaque (non-rematerializable) 16B load: forces the value to stay in VGPRs.
__device__ __forceinline__ u32x4 ld_opaque16(const __half* p) {
  u32x4 r;
  asm volatile("global_load_dwordx4 %0, %1, off" : "=v"(r) : "v"(p));
  return r;
}

// ---- zero exchange slots (every launch, replay determinism) ----
__global__ void k_init() {
  const size_t n = (size_t)NST * NN * 512;
  size_t i = (size_t)blockIdx.x * blockDim.x + threadIdx.x;
  const size_t stride = (size_t)gridDim.x * blockDim.x;
  u64* p = &g_S[0][0][0];
  for (; i < n; i += stride) p[i] = 0ull;
}

// ---- pack Whh (all stages) and Wih (non-folded stages) to fp16 ----
__global__ void k_pack(const float* __restrict__ Wih, const float* __restrict__ Whh) {
  const size_t total = (size_t)NST * NN * NN;
  size_t i = (size_t)blockIdx.x * blockDim.x + threadIdx.x;
  const size_t stride = (size_t)gridDim.x * blockDim.x;
  for (; i < total; i += stride) {
    const int st = (int)(i >> 20);
    const int m = (int)(i >> 10) & 1023;
    const int k = (int)i & 1023;
    g_W[st][m][1024 + k] = __float2half(Whh[i]);
    const int t = st >> 1, l = st & 1;
    if (l == 1 || t == 0) g_W[st][m][k] = __float2half(Wih[i]);
  }
}

// ---- fold: W'(st=2t) = Wih[st] @ linW[t-1] ----
__global__ __launch_bounds__(256) void k_fold(const float* __restrict__ Wih,
                                              const float* __restrict__ linW) {
  const int tm1 = blockIdx.z;
  const int st = (tm1 + 1) * 2;
  const float* A = Wih + (size_t)st * NN * NN;
  const float* B = linW + (size_t)tm1 * NN * NN;
  __shared__ float sA[16][68];
  __shared__ float sB[16][68];
  const int tid = threadIdx.x;
  const int tx = tid & 15, ty = tid >> 4;
  const int bm = blockIdx.y << 6, bn = blockIdx.x << 6;
  const int lm = tid & 63, lk = (tid >> 6) << 2;
  const int rr = tid >> 4, c4 = (tid & 15) << 2;
  float acc[4][4] = {};
  for (int k0 = 0; k0 < NN; k0 += 16) {
    const float4 av = *(const float4*)&A[(size_t)(bm + lm) * NN + k0 + lk];
    const float4 bv = *(const float4*)&B[(size_t)(k0 + rr) * NN + bn + c4];
    __syncthreads();
    sA[lk + 0][lm] = av.x; sA[lk + 1][lm] = av.y; sA[lk + 2][lm] = av.z; sA[lk + 3][lm] = av.w;
    sB[rr][c4 + 0] = bv.x; sB[rr][c4 + 1] = bv.y; sB[rr][c4 + 2] = bv.z; sB[rr][c4 + 3] = bv.w;
    __syncthreads();
    #pragma unroll
    for (int kk = 0; kk < 16; ++kk) {
      const float4 a4 = *(const float4*)&sA[kk][ty << 2];
      const float4 b4 = *(const float4*)&sB[kk][tx << 2];
      const float aa[4] = {a4.x, a4.y, a4.z, a4.w};
      const float bb[4] = {b4.x, b4.y, b4.z, b4.w};
      #pragma unroll
      for (int i = 0; i < 4; ++i)
        #pragma unroll
        for (int j = 0; j < 4; ++j) acc[i][j] += aa[i] * bb[j];
    }
  }
  #pragma unroll
  for (int i = 0; i < 4; ++i)
    #pragma unroll
    for (int j = 0; j < 4; ++j)
      g_W[st][bm + (ty << 2) + i][bn + (tx << 2) + j] = __float2half(acc[i][j]);
}

// ---- combined bias per stage ----
__global__ __launch_bounds__(256) void k_bias(const float* __restrict__ Wih,
    const float* __restrict__ bih, const float* __restrict__ bhh,
    const float* __restrict__ linb) {
  const int st = blockIdx.x, t = st >> 1, l = st & 1;
  const int tid = threadIdx.x;
  __shared__ float slb[NN];
  const bool folded = (l == 0 && t > 0);
  if (folded)
    for (int k = tid; k < NN; k += 256) slb[k] = linb[(size_t)(t - 1) * NN + k];
  __syncthreads();
  for (int m = tid; m < NN; m += 256) {
    float b = bih[(size_t)st * NN + m] + bhh[(size_t)st * NN + m];
    if (folded) {
      const float* wr = Wih + (size_t)st * NN * NN + (size_t)m * NN;
      float s0 = 0, s1 = 0, s2 = 0, s3 = 0;
      for (int k = 0; k < NN; k += 4) {
        const float4 w = *(const float4*)&wr[k];
        s0 += w.x * slb[k]; s1 += w.y * slb[k + 1];
        s2 += w.z * slb[k + 2]; s3 += w.w * slb[k + 3];
      }
      b += (s0 + s1) + (s2 + s3);
    }
    g_bias[st][m] = b;
  }
}

// ---- pipelined 16-stage scan, one dispatch, weights pinned in VGPRs ----
// 512 WGs x 256 thr, __launch_bounds__(256,2): all WGs resident (2 WG/CU).
// bid: stage = bid>>5, wg = bid&31 owns rows [32wg, 32wg+32).
// Lane (a=tid&7, c=tid>>3): rows woff+4a..+3, combined cols [64c,64c+64) -> 128 weight VGPRs,
// loaded via volatile asm (cannot be rematerialized -> guaranteed resident).
__global__ __launch_bounds__(256, 2) void k_phase(const float* __restrict__ x) {
  __shared__ __align__(16) unsigned char comb[4096];   // units 0..127 = X, 128..255 = H (vswz'd)
  __shared__ float spwf[32 * 33];
  const int tid = threadIdx.x;
  const int bid = blockIdx.x;
  const int st = bid >> 5;
  const int wg = bid & 31;
  const int woff = wg << 5;
  const int wid = tid >> 6;
  const int lane = tid & 63;
  const int a = tid & 7;
  const int c = tid >> 3;      // 0..31

  // Persistent weights: 4 rows x 64 cols = 32 u32x4 = 128 VGPRs (opaque loads).
  u32x4 w[4][8];
  #pragma unroll
  for (int r = 0; r < 4; ++r)
    #pragma unroll
    for (int i = 0; i < 8; ++i)
      w[r][i] = ld_opaque16(&g_W[st][woff + 4 * a + r][64 * c + 8 * i]);
  asm volatile("s_waitcnt vmcnt(0)" ::: "memory");
  __builtin_amdgcn_sched_barrier(0);

  float breg = 0.f;
  if (tid < 32) breg = g_bias[st][woff + tid];

  for (int s = 0; s < NN; ++s) {
    // ---------- gather ----------
    if (wid < 2) {
      // own h(s-1): 128 lanes x 4 slots -> H units 128+pl
      const int pl = wid * 64 + lane;
      const int pb = vswz_byte((128 + pl) * 16);
      if (s == 0) {
        *(u32x4*)&comb[pb] = (u32x4){0u, 0u, 0u, 0u};
      } else {
        const u64* sp = &g_S[st][s - 1][4 * pl];
        uint done = 0;
        while (done != 0xFu) {
          #pragma unroll
          for (int i = 0; i < 4; ++i)
            if (!(done & (1u << i))) {
              const u64 v = __hip_atomic_load(&sp[i], __ATOMIC_RELAXED, __HIP_MEMORY_SCOPE_AGENT);
              if (v >> 32) { *(uint*)&comb[pb + 4 * i] = (uint)v; done |= 1u << i; }
            }
          if (done != 0xFu) __builtin_amdgcn_s_sleep(1);
        }
      }
    } else {
      // upstream h(s) or x(s): 128 lanes -> X units pl
      const int pl = (wid - 2) * 64 + lane;
      const int pb = vswz_byte(pl * 16);
      if (st == 0) {
        const float4 f0 = *(const float4*)&x[(size_t)s * 8192 + 8 * pl];
        const float4 f1 = *(const float4*)&x[(size_t)s * 8192 + 8 * pl + 4];
        u32x4 o;
        o.x = pk2(f0.x, f0.y); o.y = pk2(f0.z, f0.w);
        o.z = pk2(f1.x, f1.y); o.w = pk2(f1.z, f1.w);
        *(u32x4*)&comb[pb] = o;
      } else {
        const u64* sp = &g_S[st - 1][s][4 * pl];
        uint done = 0;
        while (done != 0xFu) {
          #pragma unroll
          for (int i = 0; i < 4; ++i)
            if (!(done & (1u << i))) {
              const u64 v = __hip_atomic_load(&sp[i], __ATOMIC_RELAXED, __HIP_MEMORY_SCOPE_AGENT);
              if (v >> 32) { *(uint*)&comb[pb + 4 * i] = (uint)v; done |= 1u << i; }
            }
          if (done != 0xFu) __builtin_amdgcn_s_sleep(1);
        }
      }
    }
    __syncthreads();   // B1: comb ready

    // ---------- dot: 4 rows x 64 combined cols from VGPR weights ----------
    float p0 = 0.f, p1 = 0.f, p2 = 0.f, p3 = 0.f;
    #pragma unroll
    for (int i = 0; i < 8; ++i) {
      const u32x4 v = *(const u32x4*)&comb[vswz_byte((8 * c + i) * 16)];
      p0 = __builtin_amdgcn_fdot2(as_v2h(w[0][i].x), as_v2h(v.x), p0, false);
      p0 = __builtin_amdgcn_fdot2(as_v2h(w[0][i].y), as_v2h(v.y), p0, false);
      p0 = __builtin_amdgcn_fdot2(as_v2h(w[0][i].z), as_v2h(v.z), p0, false);
      p0 = __builtin_amdgcn_fdot2(as_v2h(w[0][i].w), as_v2h(v.w), p0, false);
      p1 = __builtin_amdgcn_fdot2(as_v2h(w[1][i].x), as_v2h(v.x), p1, false);
      p1 = __builtin_amdgcn_fdot2(as_v2h(w[1][i].y), as_v2h(v.y), p1, false);
      p1 = __builtin_amdgcn_fdot2(as_v2h(w[1][i].z), as_v2h(v.z), p1, false);
      p1 = __builtin_amdgcn_fdot2(as_v2h(w[1][i].w), as_v2h(v.w), p1, false);
      p2 = __builtin_amdgcn_fdot2(as_v2h(w[2][i].x), as_v2h(v.x), p2, false);
      p2 = __builtin_amdgcn_fdot2(as_v2h(w[2][i].y), as_v2h(v.y), p2, false);
      p2 = __builtin_amdgcn_fdot2(as_v2h(w[2][i].z), as_v2h(v.z), p2, false);
      p2 = __builtin_amdgcn_fdot2(as_v2h(w[2][i].w), as_v2h(v.w), p2, false);
      p3 = __builtin_amdgcn_fdot2(as_v2h(w[3][i].x), as_v2h(v.x), p3, false);
      p3 = __builtin_amdgcn_fdot2(as_v2h(w[3][i].y), as_v2h(v.y), p3, false);
      p3 = __builtin_amdgcn_fdot2(as_v2h(w[3][i].z), as_v2h(v.z), p3, false);
      p3 = __builtin_amdgcn_fdot2(as_v2h(w[3][i].w), as_v2h(v.w), p3, false);
    }
    spwf[c * 33 + 4 * a + 0] = p0;
    spwf[c * 33 + 4 * a + 1] = p1;
    spwf[c * 33 + 4 * a + 2] = p2;
    spwf[c * 33 + 4 * a + 3] = p3;
    __syncthreads();   // B2: spw ready

    // ---------- finish: wave 0 lanes 0..31 ----------
    if (tid < 32) {
      float dot = breg;
      #pragma unroll
      for (int cc = 0; cc < 32; ++cc) dot += spwf[cc * 33 + tid];
      const float hv = tanhf(dot);
      const float hp = __shfl_down(hv, 1);
      if ((tid & 1) == 0) {
        const u64 pv = (1ull << 32) | (u64)pk2(hv, hp);
        __hip_atomic_store(&g_S[st][s][wg * 16 + (tid >> 1)], pv,
                           __ATOMIC_RELAXED, __HIP_MEMORY_SCOPE_AGENT);
      }
      if (st & 1) g_Hout[st >> 1][(size_t)s * NN + woff + tid] = hv;
    }
    // no trailing barrier: next gather writes comb only before B1(s+1)
  }
}

// ---- epilogue: out[s][t][:] = g_Hout[t][s] @ linW[t]^T + linb[t] ----
__global__ __launch_bounds__(256) void k_out(const float* __restrict__ linW,
    const float* __restrict__ linb, float* __restrict__ out) {
  const int t = blockIdx.z;
  const float* A = g_Hout[t];
  const float* B = linW + (size_t)t * NN * NN;
  __shared__ float sA[16][68];
  __shared__ float sB[16][68];
  const int tid = threadIdx.x;
  const int tx = tid & 15, ty = tid >> 4;
  const int bm = blockIdx.y << 6, bn = blockIdx.x << 6;
  const int lm = tid & 63, lk = (tid >> 6) << 2;
  float acc[4][4] = {};
  for (int k0 = 0; k0 < NN; k0 += 16) {
    const float4 av = *(const float4*)&A[(size_t)(bm + lm) * NN + k0 + lk];
    const float4 bv = *(const float4*)&B[(size_t)(bn + lm) * NN + k0 + lk];
    __syncthreads();
    sA[lk + 0][lm] = av.x; sA[lk + 1][lm] = av.y; sA[lk + 2][lm] = av.z; sA[lk + 3][lm] = av.w;
    sB[lk + 0][lm] = bv.x; sB[lk + 1][lm] = bv.y; sB[lk + 2][lm] = bv.z; sB[lk + 3][lm] = bv.w;
    __syncthreads();
    #pragma unroll
    for (int kk = 0; kk < 16; ++kk) {
      const float4 a4 = *(const float4*)&sA[kk][ty << 2];
      const float4 b4 = *(const float4*)&sB[kk][tx << 2];
      const float aa[4] = {a4.x, a4.y, a4.z, a4.w};
      const float bb[4] = {b4.x, b4.y, b4.z, b4.w};
      #pragma unroll
      for (int i = 0; i < 4; ++i)
        #pragma unroll
        for (int j = 0; j < 4; ++j) acc[i][j] += aa[i] * bb[j];
    }
  }
  const int n0 = bn + (tx << 2);
  float bias[4];
  #pragma unroll
  for (int j = 0; j < 4; ++j) bias[j] = linb[(size_t)t * NN + n0 + j];
  #pragma unroll
  for (int i = 0; i < 4; ++i) {
    const int m = bm + (ty << 2) + i;
    float4 o;
    o.x = acc[i][0] + bias[0]; o.y = acc[i][1] + bias[1];
    o.z = acc[i][2] + bias[2]; o.w = acc[i][3] + bias[3];
    *(float4*)&out[(size_t)m * 8192 + (size_t)t * NN + n0] = o;
  }
}

extern "C" void kernel_launch(void* const* d_in, const int* in_sizes, int n_in,
                              void* d_out, int out_size, void* d_ws, size_t ws_size,
                              hipStream_t stream) {
  (void)in_sizes; (void)n_in; (void)out_size; (void)d_ws; (void)ws_size;
  const float* x    = (const float*)d_in[0];
  const float* Wih  = (const float*)d_in[1];
  const float* Whh  = (const float*)d_in[2];
  const float* bih  = (const float*)d_in[3];
  const float* bhh  = (const float*)d_in[4];
  const float* linW = (const float*)d_in[5];
  const float* linb = (const float*)d_in[6];
  float* out = (float*)d_out;

  k_init<<<2048, 256, 0, stream>>>();
  k_pack<<<2048, 256, 0, stream>>>(Wih, Whh);
  k_fold<<<dim3(16, 16, 7), 256, 0, stream>>>(Wih, linW);
  k_bias<<<16, 256, 0, stream>>>(Wih, bih, bhh, linb);
  k_phase<<<NST * WPS, 256, 0, stream>>>(x);
  k_out<<<dim3(16, 16, 8), 256, 0, stream>>>(linW, linb, out);
}

// Round 9
// 4345.585 us; speedup vs baseline: 5.1888x; 1.0070x over previous
//
#include <hip/hip_runtime.h>
#include <hip/hip_fp16.h>

#define NN 1024
#define NST 16
#define WPS 32                  // WGs per stage
#define ROWS 32                 // rows per WG

typedef _Float16 v2h __attribute__((ext_vector_type(2)));
typedef unsigned int uint;
typedef unsigned long long u64;
typedef unsigned int u32x4 __attribute__((ext_vector_type(4)));

// Static device scratch.
__device__ __half g_W[NST][NN][2048];      // per stage row: [Wih_eff(1024) | Whh(1024)] fp16
__device__ float g_bias[NST][NN];          // combined bias fp32
__device__ u64 g_S[NST][NN][512];          // slot q = {1<<32 | fp16 h[2q+1],h[2q]}
__device__ float g_Hout[8][NN * NN];       // h of odd stages (pre-linear), fp32

__device__ __forceinline__ v2h as_v2h(uint u) {
  union { uint u; v2h h; } c; c.u = u; return c.h;
}
__device__ __forceinline__ uint pk2(float a, float b) {
  union { v2h h; uint u; } c; c.h.x = (_Float16)a; c.h.y = (_Float16)b; return c.u;
}
// 16B-unit rotation swizzle (permutes units within 8-unit blocks -> spreads bank groups).
__device__ __forceinline__ int vswz_byte(int logical_byte) {
  const int u = logical_byte >> 4;
  const int pu = (u & ~7) | ((u + (u >> 3)) & 7);
  return (pu << 4) | (logical_byte & 15);
}
// Opaque (non-rematerializable) 16B load: forces the value to stay in VGPRs.
__device__ __forceinline__ u32x4 ld_opaque16(const __half* p) {
  u32x4 r;
  asm volatile("global_load_dwordx4 %0, %1, off" : "=v"(r) : "v"(p));
  return r;
}

// ---- zero exchange slots (every launch, replay determinism) ----
__global__ void k_init() {
  const size_t n = (size_t)NST * NN * 512;
  size_t i = (size_t)blockIdx.x * blockDim.x + threadIdx.x;
  const size_t stride = (size_t)gridDim.x * blockDim.x;
  u64* p = &g_S[0][0][0];
  for (; i < n; i += stride) p[i] = 0ull;
}

// ---- pack Whh (all stages) and Wih (non-folded stages) to fp16 ----
__global__ void k_pack(const float* __restrict__ Wih, const float* __restrict__ Whh) {
  const size_t total = (size_t)NST * NN * NN;
  size_t i = (size_t)blockIdx.x * blockDim.x + threadIdx.x;
  const size_t stride = (size_t)gridDim.x * blockDim.x;
  for (; i < total; i += stride) {
    const int st = (int)(i >> 20);
    const int m = (int)(i >> 10) & 1023;
    const int k = (int)i & 1023;
    g_W[st][m][1024 + k] = __float2half(Whh[i]);
    const int t = st >> 1, l = st & 1;
    if (l == 1 || t == 0) g_W[st][m][k] = __float2half(Wih[i]);
  }
}

// ---- fold: W'(st=2t) = Wih[st] @ linW[t-1] ----
__global__ __launch_bounds__(256) void k_fold(const float* __restrict__ Wih,
                                              const float* __restrict__ linW) {
  const int tm1 = blockIdx.z;
  const int st = (tm1 + 1) * 2;
  const float* A = Wih + (size_t)st * NN * NN;
  const float* B = linW + (size_t)tm1 * NN * NN;
  __shared__ float sA[16][68];
  __shared__ float sB[16][68];
  const int tid = threadIdx.x;
  const int tx = tid & 15, ty = tid >> 4;
  const int bm = blockIdx.y << 6, bn = blockIdx.x << 6;
  const int lm = tid & 63, lk = (tid >> 6) << 2;
  const int rr = tid >> 4, c4 = (tid & 15) << 2;
  float acc[4][4] = {};
  for (int k0 = 0; k0 < NN; k0 += 16) {
    const float4 av = *(const float4*)&A[(size_t)(bm + lm) * NN + k0 + lk];
    const float4 bv = *(const float4*)&B[(size_t)(k0 + rr) * NN + bn + c4];
    __syncthreads();
    sA[lk + 0][lm] = av.x; sA[lk + 1][lm] = av.y; sA[lk + 2][lm] = av.z; sA[lk + 3][lm] = av.w;
    sB[rr][c4 + 0] = bv.x; sB[rr][c4 + 1] = bv.y; sB[rr][c4 + 2] = bv.z; sB[rr][c4 + 3] = bv.w;
    __syncthreads();
    #pragma unroll
    for (int kk = 0; kk < 16; ++kk) {
      const float4 a4 = *(const float4*)&sA[kk][ty << 2];
      const float4 b4 = *(const float4*)&sB[kk][tx << 2];
      const float aa[4] = {a4.x, a4.y, a4.z, a4.w};
      const float bb[4] = {b4.x, b4.y, b4.z, b4.w};
      #pragma unroll
      for (int i = 0; i < 4; ++i)
        #pragma unroll
        for (int j = 0; j < 4; ++j) acc[i][j] += aa[i] * bb[j];
    }
  }
  #pragma unroll
  for (int i = 0; i < 4; ++i)
    #pragma unroll
    for (int j = 0; j < 4; ++j)
      g_W[st][bm + (ty << 2) + i][bn + (tx << 2) + j] = __float2half(acc[i][j]);
}

// ---- combined bias per stage ----
__global__ __launch_bounds__(256) void k_bias(const float* __restrict__ Wih,
    const float* __restrict__ bih, const float* __restrict__ bhh,
    const float* __restrict__ linb) {
  const int st = blockIdx.x, t = st >> 1, l = st & 1;
  const int tid = threadIdx.x;
  __shared__ float slb[NN];
  const bool folded = (l == 0 && t > 0);
  if (folded)
    for (int k = tid; k < NN; k += 256) slb[k] = linb[(size_t)(t - 1) * NN + k];
  __syncthreads();
  for (int m = tid; m < NN; m += 256) {
    float b = bih[(size_t)st * NN + m] + bhh[(size_t)st * NN + m];
    if (folded) {
      const float* wr = Wih + (size_t)st * NN * NN + (size_t)m * NN;
      float s0 = 0, s1 = 0, s2 = 0, s3 = 0;
      for (int k = 0; k < NN; k += 4) {
        const float4 w = *(const float4*)&wr[k];
        s0 += w.x * slb[k]; s1 += w.y * slb[k + 1];
        s2 += w.z * slb[k + 2]; s3 += w.w * slb[k + 3];
      }
      b += (s0 + s1) + (s2 + s3);
    }
    g_bias[st][m] = b;
  }
}

// ---- pipelined 16-stage scan, one dispatch, weights pinned in 32 NAMED u32x4 VGPRs ----
// 512 WGs x 256 thr, __launch_bounds__(256,2): all WGs resident (2 WG/CU).
// bid: stage = bid>>5, wg = bid&31 owns rows [32wg, 32wg+32).
// Lane (a=tid&7, c=tid>>3): rows woff+4a..+3, combined cols [64c,64c+64).
// Rule-#20 fix: NO weight array -- 32 named variables, fully hand-unrolled.
__global__ __launch_bounds__(256, 2) void k_phase(const float* __restrict__ x) {
  __shared__ __align__(16) unsigned char comb[4096];   // units 0..127 = X, 128..255 = H (vswz'd)
  __shared__ float spwf[32 * 33];
  const int tid = threadIdx.x;
  const int bid = blockIdx.x;
  const int st = bid >> 5;
  const int wg = bid & 31;
  const int woff = wg << 5;
  const int wid = tid >> 6;
  const int lane = tid & 63;
  const int a = tid & 7;
  const int c = tid >> 3;      // 0..31

#define LDW(RR, II) ld_opaque16(&g_W[st][woff + 4 * a + (RR)][64 * c + 8 * (II)])
  u32x4 w00 = LDW(0,0), w01 = LDW(0,1), w02 = LDW(0,2), w03 = LDW(0,3);
  u32x4 w04 = LDW(0,4), w05 = LDW(0,5), w06 = LDW(0,6), w07 = LDW(0,7);
  u32x4 w10 = LDW(1,0), w11 = LDW(1,1), w12 = LDW(1,2), w13 = LDW(1,3);
  u32x4 w14 = LDW(1,4), w15 = LDW(1,5), w16 = LDW(1,6), w17 = LDW(1,7);
  u32x4 w20 = LDW(2,0), w21 = LDW(2,1), w22 = LDW(2,2), w23 = LDW(2,3);
  u32x4 w24 = LDW(2,4), w25 = LDW(2,5), w26 = LDW(2,6), w27 = LDW(2,7);
  u32x4 w30 = LDW(3,0), w31 = LDW(3,1), w32 = LDW(3,2), w33 = LDW(3,3);
  u32x4 w34 = LDW(3,4), w35 = LDW(3,5), w36 = LDW(3,6), w37 = LDW(3,7);
#undef LDW
  asm volatile("s_waitcnt vmcnt(0)" ::: "memory");
  __builtin_amdgcn_sched_barrier(0);

  float breg = 0.f;
  if (tid < 32) breg = g_bias[st][woff + tid];

  for (int s = 0; s < NN; ++s) {
    // ---------- gather ----------
    if (wid < 2) {
      // own h(s-1): 128 lanes x 4 slots -> H units 128+pl
      const int pl = wid * 64 + lane;
      const int pb = vswz_byte((128 + pl) * 16);
      if (s == 0) {
        *(u32x4*)&comb[pb] = (u32x4){0u, 0u, 0u, 0u};
      } else {
        const u64* sp = &g_S[st][s - 1][4 * pl];
        uint done = 0;
        while (done != 0xFu) {
          #pragma unroll
          for (int i = 0; i < 4; ++i)
            if (!(done & (1u << i))) {
              const u64 v = __hip_atomic_load(&sp[i], __ATOMIC_RELAXED, __HIP_MEMORY_SCOPE_AGENT);
              if (v >> 32) { *(uint*)&comb[pb + 4 * i] = (uint)v; done |= 1u << i; }
            }
          if (done != 0xFu) __builtin_amdgcn_s_sleep(1);
        }
      }
    } else {
      // upstream h(s) or x(s): 128 lanes -> X units pl
      const int pl = (wid - 2) * 64 + lane;
      const int pb = vswz_byte(pl * 16);
      if (st == 0) {
        const float4 f0 = *(const float4*)&x[(size_t)s * 8192 + 8 * pl];
        const float4 f1 = *(const float4*)&x[(size_t)s * 8192 + 8 * pl + 4];
        u32x4 o;
        o.x = pk2(f0.x, f0.y); o.y = pk2(f0.z, f0.w);
        o.z = pk2(f1.x, f1.y); o.w = pk2(f1.z, f1.w);
        *(u32x4*)&comb[pb] = o;
      } else {
        const u64* sp = &g_S[st - 1][s][4 * pl];
        uint done = 0;
        while (done != 0xFu) {
          #pragma unroll
          for (int i = 0; i < 4; ++i)
            if (!(done & (1u << i))) {
              const u64 v = __hip_atomic_load(&sp[i], __ATOMIC_RELAXED, __HIP_MEMORY_SCOPE_AGENT);
              if (v >> 32) { *(uint*)&comb[pb + 4 * i] = (uint)v; done |= 1u << i; }
            }
          if (done != 0xFu) __builtin_amdgcn_s_sleep(1);
        }
      }
    }
    __syncthreads();   // B1: comb ready

    // ---------- dot: 4 rows x 64 combined cols, fully static references ----------
    float p0 = 0.f, p1 = 0.f, p2 = 0.f, p3 = 0.f;
#define DOTSTEP(II, A0, A1, A2, A3) { \
      const u32x4 v = *(const u32x4*)&comb[vswz_byte((8 * c + (II)) * 16)]; \
      p0 = __builtin_amdgcn_fdot2(as_v2h(A0.x), as_v2h(v.x), p0, false); \
      p0 = __builtin_amdgcn_fdot2(as_v2h(A0.y), as_v2h(v.y), p0, false); \
      p0 = __builtin_amdgcn_fdot2(as_v2h(A0.z), as_v2h(v.z), p0, false); \
      p0 = __builtin_amdgcn_fdot2(as_v2h(A0.w), as_v2h(v.w), p0, false); \
      p1 = __builtin_amdgcn_fdot2(as_v2h(A1.x), as_v2h(v.x), p1, false); \
      p1 = __builtin_amdgcn_fdot2(as_v2h(A1.y), as_v2h(v.y), p1, false); \
      p1 = __builtin_amdgcn_fdot2(as_v2h(A1.z), as_v2h(v.z), p1, false); \
      p1 = __builtin_amdgcn_fdot2(as_v2h(A1.w), as_v2h(v.w), p1, false); \
      p2 = __builtin_amdgcn_fdot2(as_v2h(A2.x), as_v2h(v.x), p2, false); \
      p2 = __builtin_amdgcn_fdot2(as_v2h(A2.y), as_v2h(v.y), p2, false); \
      p2 = __builtin_amdgcn_fdot2(as_v2h(A2.z), as_v2h(v.z), p2, false); \
      p2 = __builtin_amdgcn_fdot2(as_v2h(A2.w), as_v2h(v.w), p2, false); \
      p3 = __builtin_amdgcn_fdot2(as_v2h(A3.x), as_v2h(v.x), p3, false); \
      p3 = __builtin_amdgcn_fdot2(as_v2h(A3.y), as_v2h(v.y), p3, false); \
      p3 = __builtin_amdgcn_fdot2(as_v2h(A3.z), as_v2h(v.z), p3, false); \
      p3 = __builtin_amdgcn_fdot2(as_v2h(A3.w), as_v2h(v.w), p3, false); }
    DOTSTEP(0, w00, w10, w20, w30)
    DOTSTEP(1, w01, w11, w21, w31)
    DOTSTEP(2, w02, w12, w22, w32)
    DOTSTEP(3, w03, w13, w23, w33)
    DOTSTEP(4, w04, w14, w24, w34)
    DOTSTEP(5, w05, w15, w25, w35)
    DOTSTEP(6, w06, w16, w26, w36)
    DOTSTEP(7, w07, w17, w27, w37)
#undef DOTSTEP
    spwf[c * 33 + 4 * a + 0] = p0;
    spwf[c * 33 + 4 * a + 1] = p1;
    spwf[c * 33 + 4 * a + 2] = p2;
    spwf[c * 33 + 4 * a + 3] = p3;
    __syncthreads();   // B2: spw ready

    // ---------- finish: wave 0 lanes 0..31 ----------
    if (tid < 32) {
      float dot = breg;
      #pragma unroll
      for (int cc = 0; cc < 32; ++cc) dot += spwf[cc * 33 + tid];
      const float hv = tanhf(dot);
      const float hp = __shfl_down(hv, 1);
      if ((tid & 1) == 0) {
        const u64 pv = (1ull << 32) | (u64)pk2(hv, hp);
        __hip_atomic_store(&g_S[st][s][wg * 16 + (tid >> 1)], pv,
                           __ATOMIC_RELAXED, __HIP_MEMORY_SCOPE_AGENT);
      }
      if (st & 1) g_Hout[st >> 1][(size_t)s * NN + woff + tid] = hv;
    }
    // no trailing barrier: next gather writes comb only before B1(s+1)
  }
}

// ---- epilogue: out[s][t][:] = g_Hout[t][s] @ linW[t]^T + linb[t] ----
__global__ __launch_bounds__(256) void k_out(const float* __restrict__ linW,
    const float* __restrict__ linb, float* __restrict__ out) {
  const int t = blockIdx.z;
  const float* A = g_Hout[t];
  const float* B = linW + (size_t)t * NN * NN;
  __shared__ float sA[16][68];
  __shared__ float sB[16][68];
  const int tid = threadIdx.x;
  const int tx = tid & 15, ty = tid >> 4;
  const int bm = blockIdx.y << 6, bn = blockIdx.x << 6;
  const int lm = tid & 63, lk = (tid >> 6) << 2;
  float acc[4][4] = {};
  for (int k0 = 0; k0 < NN; k0 += 16) {
    const float4 av = *(const float4*)&A[(size_t)(bm + lm) * NN + k0 + lk];
    const float4 bv = *(const float4*)&B[(size_t)(bn + lm) * NN + k0 + lk];
    __syncthreads();
    sA[lk + 0][lm] = av.x; sA[lk + 1][lm] = av.y; sA[lk + 2][lm] = av.z; sA[lk + 3][lm] = av.w;
    sB[lk + 0][lm] = bv.x; sB[lk + 1][lm] = bv.y; sB[lk + 2][lm] = bv.z; sB[lk + 3][lm] = bv.w;
    __syncthreads();
    #pragma unroll
    for (int kk = 0; kk < 16; ++kk) {
      const float4 a4 = *(const float4*)&sA[kk][ty << 2];
      const float4 b4 = *(const float4*)&sB[kk][tx << 2];
      const float aa[4] = {a4.x, a4.y, a4.z, a4.w};
      const float bb[4] = {b4.x, b4.y, b4.z, b4.w};
      #pragma unroll
      for (int i = 0; i < 4; ++i)
        #pragma unroll
        for (int j = 0; j < 4; ++j) acc[i][j] += aa[i] * bb[j];
    }
  }
  const int n0 = bn + (tx << 2);
  float bias[4];
  #pragma unroll
  for (int j = 0; j < 4; ++j) bias[j] = linb[(size_t)t * NN + n0 + j];
  #pragma unroll
  for (int i = 0; i < 4; ++i) {
    const int m = bm + (ty << 2) + i;
    float4 o;
    o.x = acc[i][0] + bias[0]; o.y = acc[i][1] + bias[1];
    o.z = acc[i][2] + bias[2]; o.w = acc[i][3] + bias[3];
    *(float4*)&out[(size_t)m * 8192 + (size_t)t * NN + n0] = o;
  }
}

extern "C" void kernel_launch(void* const* d_in, const int* in_sizes, int n_in,
                              void* d_out, int out_size, void* d_ws, size_t ws_size,
                              hipStream_t stream) {
  (void)in_sizes; (void)n_in; (void)out_size; (void)d_ws; (void)ws_size;
  const float* x    = (const float*)d_in[0];
  const float* Wih  = (const float*)d_in[1];
  const float* Whh  = (const float*)d_in[2];
  const float* bih  = (const float*)d_in[3];
  const float* bhh  = (const float*)d_in[4];
  const float* linW = (const float*)d_in[5];
  const float* linb = (const float*)d_in[6];
  float* out = (float*)d_out;

  k_init<<<2048, 256, 0, stream>>>();
  k_pack<<<2048, 256, 0, stream>>>(Wih, Whh);
  k_fold<<<dim3(16, 16, 7), 256, 0, stream>>>(Wih, linW);
  k_bias<<<16, 256, 0, stream>>>(Wih, bih, bhh, linb);
  k_phase<<<NST * WPS, 256, 0, stream>>>(x);
  k_out<<<dim3(16, 16, 8), 256, 0, stream>>>(linW, linb, out);
}

// Round 10
// 4342.893 us; speedup vs baseline: 5.1920x; 1.0006x over previous
//
#include <hip/hip_runtime.h>
#include <hip/hip_fp16.h>

#define NN 1024
#define NST 16
#define WPS 32                  // WGs per stage
#define ROWS 32                 // rows per WG

typedef _Float16 v2h __attribute__((ext_vector_type(2)));
typedef unsigned int uint;
typedef unsigned long long u64;
typedef unsigned int u32x4 __attribute__((ext_vector_type(4)));

// Static device scratch.
__device__ __half g_W[NST][NN][2048];      // per stage row: [Wih_eff(1024) | Whh(1024)] fp16
__device__ float g_bias[NST][NN];          // combined bias fp32
__device__ u64 g_S[NST][NN][512];          // slot q = {1<<32 | fp16 h[2q+1],h[2q]}
__device__ float g_Hout[8][NN * NN];       // h of odd stages (pre-linear), fp32

__device__ __forceinline__ v2h as_v2h(uint u) {
  union { uint u; v2h h; } c; c.u = u; return c.h;
}
__device__ __forceinline__ uint pk2(float a, float b) {
  union { v2h h; uint u; } c; c.h.x = (_Float16)a; c.h.y = (_Float16)b; return c.u;
}
// 16B-unit rotation swizzle (permutes units within 8-unit blocks -> spreads bank groups).
__device__ __forceinline__ int vswz_byte(int logical_byte) {
  const int u = logical_byte >> 4;
  const int pu = (u & ~7) | ((u + (u >> 3)) & 7);
  return (pu << 4) | (logical_byte & 15);
}
// Opaque (non-rematerializable) 16B load: forces the value to stay in VGPRs.
__device__ __forceinline__ u32x4 ld_opaque16(const __half* p) {
  u32x4 r;
  asm volatile("global_load_dwordx4 %0, %1, off" : "=v"(r) : "v"(p));
  return r;
}

// ---- zero exchange slots (every launch, replay determinism) ----
__global__ void k_init() {
  const size_t n = (size_t)NST * NN * 512;
  size_t i = (size_t)blockIdx.x * blockDim.x + threadIdx.x;
  const size_t stride = (size_t)gridDim.x * blockDim.x;
  u64* p = &g_S[0][0][0];
  for (; i < n; i += stride) p[i] = 0ull;
}

// ---- pack Whh (all stages) and Wih (non-folded stages) to fp16 ----
__global__ void k_pack(const float* __restrict__ Wih, const float* __restrict__ Whh) {
  const size_t total = (size_t)NST * NN * NN;
  size_t i = (size_t)blockIdx.x * blockDim.x + threadIdx.x;
  const size_t stride = (size_t)gridDim.x * blockDim.x;
  for (; i < total; i += stride) {
    const int st = (int)(i >> 20);
    const int m = (int)(i >> 10) & 1023;
    const int k = (int)i & 1023;
    g_W[st][m][1024 + k] = __float2half(Whh[i]);
    const int t = st >> 1, l = st & 1;
    if (l == 1 || t == 0) g_W[st][m][k] = __float2half(Wih[i]);
  }
}

// ---- fold: W'(st=2t) = Wih[st] @ linW[t-1] ----
__global__ __launch_bounds__(256) void k_fold(const float* __restrict__ Wih,
                                              const float* __restrict__ linW) {
  const int tm1 = blockIdx.z;
  const int st = (tm1 + 1) * 2;
  const float* A = Wih + (size_t)st * NN * NN;
  const float* B = linW + (size_t)tm1 * NN * NN;
  __shared__ float sA[16][68];
  __shared__ float sB[16][68];
  const int tid = threadIdx.x;
  const int tx = tid & 15, ty = tid >> 4;
  const int bm = blockIdx.y << 6, bn = blockIdx.x << 6;
  const int lm = tid & 63, lk = (tid >> 6) << 2;
  const int rr = tid >> 4, c4 = (tid & 15) << 2;
  float acc[4][4] = {};
  for (int k0 = 0; k0 < NN; k0 += 16) {
    const float4 av = *(const float4*)&A[(size_t)(bm + lm) * NN + k0 + lk];
    const float4 bv = *(const float4*)&B[(size_t)(k0 + rr) * NN + bn + c4];
    __syncthreads();
    sA[lk + 0][lm] = av.x; sA[lk + 1][lm] = av.y; sA[lk + 2][lm] = av.z; sA[lk + 3][lm] = av.w;
    sB[rr][c4 + 0] = bv.x; sB[rr][c4 + 1] = bv.y; sB[rr][c4 + 2] = bv.z; sB[rr][c4 + 3] = bv.w;
    __syncthreads();
    #pragma unroll
    for (int kk = 0; kk < 16; ++kk) {
      const float4 a4 = *(const float4*)&sA[kk][ty << 2];
      const float4 b4 = *(const float4*)&sB[kk][tx << 2];
      const float aa[4] = {a4.x, a4.y, a4.z, a4.w};
      const float bb[4] = {b4.x, b4.y, b4.z, b4.w};
      #pragma unroll
      for (int i = 0; i < 4; ++i)
        #pragma unroll
        for (int j = 0; j < 4; ++j) acc[i][j] += aa[i] * bb[j];
    }
  }
  #pragma unroll
  for (int i = 0; i < 4; ++i)
    #pragma unroll
    for (int j = 0; j < 4; ++j)
      g_W[st][bm + (ty << 2) + i][bn + (tx << 2) + j] = __float2half(acc[i][j]);
}

// ---- combined bias per stage ----
__global__ __launch_bounds__(256) void k_bias(const float* __restrict__ Wih,
    const float* __restrict__ bih, const float* __restrict__ bhh,
    const float* __restrict__ linb) {
  const int st = blockIdx.x, t = st >> 1, l = st & 1;
  const int tid = threadIdx.x;
  __shared__ float slb[NN];
  const bool folded = (l == 0 && t > 0);
  if (folded)
    for (int k = tid; k < NN; k += 256) slb[k] = linb[(size_t)(t - 1) * NN + k];
  __syncthreads();
  for (int m = tid; m < NN; m += 256) {
    float b = bih[(size_t)st * NN + m] + bhh[(size_t)st * NN + m];
    if (folded) {
      const float* wr = Wih + (size_t)st * NN * NN + (size_t)m * NN;
      float s0 = 0, s1 = 0, s2 = 0, s3 = 0;
      for (int k = 0; k < NN; k += 4) {
        const float4 w = *(const float4*)&wr[k];
        s0 += w.x * slb[k]; s1 += w.y * slb[k + 1];
        s2 += w.z * slb[k + 2]; s3 += w.w * slb[k + 3];
      }
      b += (s0 + s1) + (s2 + s3);
    }
    g_bias[st][m] = b;
  }
}

// ---- pipelined 16-stage scan, one dispatch, weights pinned in 32 NAMED u32x4 VGPRs ----
// 512 WGs x 256 thr; amdgpu_waves_per_eu(2,2): pressure target = 256 regs (2 waves/EU),
// so the allocator has NO reason to spill the 128 weight VGPRs. 2 WG/CU -> all resident.
// bid: stage = bid>>5, wg = bid&31 owns rows [32wg, 32wg+32).
// Lane (a=tid&7, c=tid>>3): rows woff+4a..+3, combined cols [64c,64c+64).
__global__ __launch_bounds__(256)
__attribute__((amdgpu_waves_per_eu(2, 2)))
void k_phase(const float* __restrict__ x) {
  __shared__ __align__(16) unsigned char comb[4096];   // units 0..127 = X, 128..255 = H (vswz'd)
  __shared__ float spwf[32 * 33];
  const int tid = threadIdx.x;
  const int bid = blockIdx.x;
  const int st = bid >> 5;
  const int wg = bid & 31;
  const int woff = wg << 5;
  const int wid = tid >> 6;
  const int lane = tid & 63;
  const int a = tid & 7;
  const int c = tid >> 3;      // 0..31

#define LDW(RR, II) ld_opaque16(&g_W[st][woff + 4 * a + (RR)][64 * c + 8 * (II)])
  u32x4 w00 = LDW(0,0), w01 = LDW(0,1), w02 = LDW(0,2), w03 = LDW(0,3);
  u32x4 w04 = LDW(0,4), w05 = LDW(0,5), w06 = LDW(0,6), w07 = LDW(0,7);
  u32x4 w10 = LDW(1,0), w11 = LDW(1,1), w12 = LDW(1,2), w13 = LDW(1,3);
  u32x4 w14 = LDW(1,4), w15 = LDW(1,5), w16 = LDW(1,6), w17 = LDW(1,7);
  u32x4 w20 = LDW(2,0), w21 = LDW(2,1), w22 = LDW(2,2), w23 = LDW(2,3);
  u32x4 w24 = LDW(2,4), w25 = LDW(2,5), w26 = LDW(2,6), w27 = LDW(2,7);
  u32x4 w30 = LDW(3,0), w31 = LDW(3,1), w32 = LDW(3,2), w33 = LDW(3,3);
  u32x4 w34 = LDW(3,4), w35 = LDW(3,5), w36 = LDW(3,6), w37 = LDW(3,7);
#undef LDW
  asm volatile("s_waitcnt vmcnt(0)" ::: "memory");
  __builtin_amdgcn_sched_barrier(0);

  float breg = 0.f;
  if (tid < 32) breg = g_bias[st][woff + tid];

  for (int s = 0; s < NN; ++s) {
    // ---------- gather ----------
    if (wid < 2) {
      // own h(s-1): 128 lanes x 4 slots -> H units 128+pl
      const int pl = wid * 64 + lane;
      const int pb = vswz_byte((128 + pl) * 16);
      if (s == 0) {
        *(u32x4*)&comb[pb] = (u32x4){0u, 0u, 0u, 0u};
      } else {
        const u64* sp = &g_S[st][s - 1][4 * pl];
        uint done = 0;
        while (done != 0xFu) {
          #pragma unroll
          for (int i = 0; i < 4; ++i)
            if (!(done & (1u << i))) {
              const u64 v = __hip_atomic_load(&sp[i], __ATOMIC_RELAXED, __HIP_MEMORY_SCOPE_AGENT);
              if (v >> 32) { *(uint*)&comb[pb + 4 * i] = (uint)v; done |= 1u << i; }
            }
          if (done != 0xFu) __builtin_amdgcn_s_sleep(1);
        }
      }
    } else {
      // upstream h(s) or x(s): 128 lanes -> X units pl
      const int pl = (wid - 2) * 64 + lane;
      const int pb = vswz_byte(pl * 16);
      if (st == 0) {
        const float4 f0 = *(const float4*)&x[(size_t)s * 8192 + 8 * pl];
        const float4 f1 = *(const float4*)&x[(size_t)s * 8192 + 8 * pl + 4];
        u32x4 o;
        o.x = pk2(f0.x, f0.y); o.y = pk2(f0.z, f0.w);
        o.z = pk2(f1.x, f1.y); o.w = pk2(f1.z, f1.w);
        *(u32x4*)&comb[pb] = o;
      } else {
        const u64* sp = &g_S[st - 1][s][4 * pl];
        uint done = 0;
        while (done != 0xFu) {
          #pragma unroll
          for (int i = 0; i < 4; ++i)
            if (!(done & (1u << i))) {
              const u64 v = __hip_atomic_load(&sp[i], __ATOMIC_RELAXED, __HIP_MEMORY_SCOPE_AGENT);
              if (v >> 32) { *(uint*)&comb[pb + 4 * i] = (uint)v; done |= 1u << i; }
            }
          if (done != 0xFu) __builtin_amdgcn_s_sleep(1);
        }
      }
    }
    __syncthreads();   // B1: comb ready

    // ---------- dot: 4 rows x 64 combined cols, fully static references ----------
    float p0 = 0.f, p1 = 0.f, p2 = 0.f, p3 = 0.f;
#define DOTSTEP(II, A0, A1, A2, A3) { \
      const u32x4 v = *(const u32x4*)&comb[vswz_byte((8 * c + (II)) * 16)]; \
      p0 = __builtin_amdgcn_fdot2(as_v2h(A0.x), as_v2h(v.x), p0, false); \
      p0 = __builtin_amdgcn_fdot2(as_v2h(A0.y), as_v2h(v.y), p0, false); \
      p0 = __builtin_amdgcn_fdot2(as_v2h(A0.z), as_v2h(v.z), p0, false); \
      p0 = __builtin_amdgcn_fdot2(as_v2h(A0.w), as_v2h(v.w), p0, false); \
      p1 = __builtin_amdgcn_fdot2(as_v2h(A1.x), as_v2h(v.x), p1, false); \
      p1 = __builtin_amdgcn_fdot2(as_v2h(A1.y), as_v2h(v.y), p1, false); \
      p1 = __builtin_amdgcn_fdot2(as_v2h(A1.z), as_v2h(v.z), p1, false); \
      p1 = __builtin_amdgcn_fdot2(as_v2h(A1.w), as_v2h(v.w), p1, false); \
      p2 = __builtin_amdgcn_fdot2(as_v2h(A2.x), as_v2h(v.x), p2, false); \
      p2 = __builtin_amdgcn_fdot2(as_v2h(A2.y), as_v2h(v.y), p2, false); \
      p2 = __builtin_amdgcn_fdot2(as_v2h(A2.z), as_v2h(v.z), p2, false); \
      p2 = __builtin_amdgcn_fdot2(as_v2h(A2.w), as_v2h(v.w), p2, false); \
      p3 = __builtin_amdgcn_fdot2(as_v2h(A3.x), as_v2h(v.x), p3, false); \
      p3 = __builtin_amdgcn_fdot2(as_v2h(A3.y), as_v2h(v.y), p3, false); \
      p3 = __builtin_amdgcn_fdot2(as_v2h(A3.z), as_v2h(v.z), p3, false); \
      p3 = __builtin_amdgcn_fdot2(as_v2h(A3.w), as_v2h(v.w), p3, false); }
    DOTSTEP(0, w00, w10, w20, w30)
    DOTSTEP(1, w01, w11, w21, w31)
    DOTSTEP(2, w02, w12, w22, w32)
    DOTSTEP(3, w03, w13, w23, w33)
    DOTSTEP(4, w04, w14, w24, w34)
    DOTSTEP(5, w05, w15, w25, w35)
    DOTSTEP(6, w06, w16, w26, w36)
    DOTSTEP(7, w07, w17, w27, w37)
#undef DOTSTEP
    spwf[c * 33 + 4 * a + 0] = p0;
    spwf[c * 33 + 4 * a + 1] = p1;
    spwf[c * 33 + 4 * a + 2] = p2;
    spwf[c * 33 + 4 * a + 3] = p3;
    __syncthreads();   // B2: spw ready

    // ---------- finish: wave 0 lanes 0..31 ----------
    if (tid < 32) {
      float dot = breg;
      #pragma unroll
      for (int cc = 0; cc < 32; ++cc) dot += spwf[cc * 33 + tid];
      const float hv = tanhf(dot);
      const float hp = __shfl_down(hv, 1);
      if ((tid & 1) == 0) {
        const u64 pv = (1ull << 32) | (u64)pk2(hv, hp);
        __hip_atomic_store(&g_S[st][s][wg * 16 + (tid >> 1)], pv,
                           __ATOMIC_RELAXED, __HIP_MEMORY_SCOPE_AGENT);
      }
      if (st & 1) g_Hout[st >> 1][(size_t)s * NN + woff + tid] = hv;
    }
    // no trailing barrier: next gather writes comb only before B1(s+1)
  }
}

// ---- epilogue: out[s][t][:] = g_Hout[t][s] @ linW[t]^T + linb[t] ----
__global__ __launch_bounds__(256) void k_out(const float* __restrict__ linW,
    const float* __restrict__ linb, float* __restrict__ out) {
  const int t = blockIdx.z;
  const float* A = g_Hout[t];
  const float* B = linW + (size_t)t * NN * NN;
  __shared__ float sA[16][68];
  __shared__ float sB[16][68];
  const int tid = threadIdx.x;
  const int tx = tid & 15, ty = tid >> 4;
  const int bm = blockIdx.y << 6, bn = blockIdx.x << 6;
  const int lm = tid & 63, lk = (tid >> 6) << 2;
  float acc[4][4] = {};
  for (int k0 = 0; k0 < NN; k0 += 16) {
    const float4 av = *(const float4*)&A[(size_t)(bm + lm) * NN + k0 + lk];
    const float4 bv = *(const float4*)&B[(size_t)(bn + lm) * NN + k0 + lk];
    __syncthreads();
    sA[lk + 0][lm] = av.x; sA[lk + 1][lm] = av.y; sA[lk + 2][lm] = av.z; sA[lk + 3][lm] = av.w;
    sB[lk + 0][lm] = bv.x; sB[lk + 1][lm] = bv.y; sB[lk + 2][lm] = bv.z; sB[lk + 3][lm] = bv.w;
    __syncthreads();
    #pragma unroll
    for (int kk = 0; kk < 16; ++kk) {
      const float4 a4 = *(const float4*)&sA[kk][ty << 2];
      const float4 b4 = *(const float4*)&sB[kk][tx << 2];
      const float aa[4] = {a4.x, a4.y, a4.z, a4.w};
      const float bb[4] = {b4.x, b4.y, b4.z, b4.w};
      #pragma unroll
      for (int i = 0; i < 4; ++i)
        #pragma unroll
        for (int j = 0; j < 4; ++j) acc[i][j] += aa[i] * bb[j];
    }
  }
  const int n0 = bn + (tx << 2);
  float bias[4];
  #pragma unroll
  for (int j = 0; j < 4; ++j) bias[j] = linb[(size_t)t * NN + n0 + j];
  #pragma unroll
  for (int i = 0; i < 4; ++i) {
    const int m = bm + (ty << 2) + i;
    float4 o;
    o.x = acc[i][0] + bias[0]; o.y = acc[i][1] + bias[1];
    o.z = acc[i][2] + bias[2]; o.w = acc[i][3] + bias[3];
    *(float4*)&out[(size_t)m * 8192 + (size_t)t * NN + n0] = o;
  }
}

extern "C" void kernel_launch(void* const* d_in, const int* in_sizes, int n_in,
                              void* d_out, int out_size, void* d_ws, size_t ws_size,
                              hipStream_t stream) {
  (void)in_sizes; (void)n_in; (void)out_size; (void)d_ws; (void)ws_size;
  const float* x    = (const float*)d_in[0];
  const float* Wih  = (const float*)d_in[1];
  const float* Whh  = (const float*)d_in[2];
  const float* bih  = (const float*)d_in[3];
  const float* bhh  = (const float*)d_in[4];
  const float* linW = (const float*)d_in[5];
  const float* linb = (const float*)d_in[6];
  float* out = (float*)d_out;

  k_init<<<2048, 256, 0, stream>>>();
  k_pack<<<2048, 256, 0, stream>>>(Wih, Whh);
  k_fold<<<dim3(16, 16, 7), 256, 0, stream>>>(Wih, linW);
  k_bias<<<16, 256, 0, stream>>>(Wih, bih, bhh, linb);
  k_phase<<<NST * WPS, 256, 0, stream>>>(x);
  k_out<<<dim3(16, 16, 8), 256, 0, stream>>>(linW, linb, out);
}

// Round 11
// 3379.193 us; speedup vs baseline: 6.6727x; 1.2852x over previous
//
#include <hip/hip_runtime.h>
#include <hip/hip_fp16.h>

#define NN 1024
#define NST 16
#define WPS 16                  // WGs per stage
#define WROWS 64                // rows per WG

typedef _Float16 v2h __attribute__((ext_vector_type(2)));
typedef unsigned int uint;
typedef unsigned long long u64;
typedef unsigned int u32x4 __attribute__((ext_vector_type(4)));

// Static device scratch.
__device__ __half g_W[NST][NN][2048];      // per stage row: [Wih_eff(1024) | Whh(1024)] fp16
__device__ float g_bias[NST][NN];          // combined bias fp32
__device__ u64 g_S[NST][NN][512];          // slot q = {1<<32 | fp16 h[2q+1],h[2q]}
__device__ float g_Hout[8][NN * NN];       // h of odd stages (pre-linear), fp32

__device__ __forceinline__ v2h as_v2h(uint u) {
  union { uint u; v2h h; } c; c.u = u; return c.h;
}
__device__ __forceinline__ uint pk2(float a, float b) {
  union { v2h h; uint u; } c; c.h.x = (_Float16)a; c.h.y = (_Float16)b; return c.u;
}
// 16B-unit swizzle: low3' = (u + (u>>5)) & 7 -> the 8 c-groups (stride 32 units)
// land in 8 distinct bank groups for every DOTSTEP read.
__device__ __forceinline__ int swzu(int u) {
  return (u & ~7) | ((u + (u >> 5)) & 7);
}
// Opaque (non-rematerializable) 16B load.
__device__ __forceinline__ u32x4 ld_opaque16(const __half* p) {
  u32x4 r;
  asm volatile("global_load_dwordx4 %0, %1, off" : "=v"(r) : "v"(p));
  return r;
}

// ---- zero exchange slots (every launch, replay determinism) ----
__global__ void k_init() {
  const size_t n = (size_t)NST * NN * 512;
  size_t i = (size_t)blockIdx.x * blockDim.x + threadIdx.x;
  const size_t stride = (size_t)gridDim.x * blockDim.x;
  u64* p = &g_S[0][0][0];
  for (; i < n; i += stride) p[i] = 0ull;
}

// ---- pack Whh (all stages) and Wih (non-folded stages) to fp16 ----
__global__ void k_pack(const float* __restrict__ Wih, const float* __restrict__ Whh) {
  const size_t total = (size_t)NST * NN * NN;
  size_t i = (size_t)blockIdx.x * blockDim.x + threadIdx.x;
  const size_t stride = (size_t)gridDim.x * blockDim.x;
  for (; i < total; i += stride) {
    const int st = (int)(i >> 20);
    const int m = (int)(i >> 10) & 1023;
    const int k = (int)i & 1023;
    g_W[st][m][1024 + k] = __float2half(Whh[i]);
    const int t = st >> 1, l = st & 1;
    if (l == 1 || t == 0) g_W[st][m][k] = __float2half(Wih[i]);
  }
}

// ---- fold: W'(st=2t) = Wih[st] @ linW[t-1] ----
__global__ __launch_bounds__(256) void k_fold(const float* __restrict__ Wih,
                                              const float* __restrict__ linW) {
  const int tm1 = blockIdx.z;
  const int st = (tm1 + 1) * 2;
  const float* A = Wih + (size_t)st * NN * NN;
  const float* B = linW + (size_t)tm1 * NN * NN;
  __shared__ float sA[16][68];
  __shared__ float sB[16][68];
  const int tid = threadIdx.x;
  const int tx = tid & 15, ty = tid >> 4;
  const int bm = blockIdx.y << 6, bn = blockIdx.x << 6;
  const int lm = tid & 63, lk = (tid >> 6) << 2;
  const int rr = tid >> 4, c4 = (tid & 15) << 2;
  float acc[4][4] = {};
  for (int k0 = 0; k0 < NN; k0 += 16) {
    const float4 av = *(const float4*)&A[(size_t)(bm + lm) * NN + k0 + lk];
    const float4 bv = *(const float4*)&B[(size_t)(k0 + rr) * NN + bn + c4];
    __syncthreads();
    sA[lk + 0][lm] = av.x; sA[lk + 1][lm] = av.y; sA[lk + 2][lm] = av.z; sA[lk + 3][lm] = av.w;
    sB[rr][c4 + 0] = bv.x; sB[rr][c4 + 1] = bv.y; sB[rr][c4 + 2] = bv.z; sB[rr][c4 + 3] = bv.w;
    __syncthreads();
    #pragma unroll
    for (int kk = 0; kk < 16; ++kk) {
      const float4 a4 = *(const float4*)&sA[kk][ty << 2];
      const float4 b4 = *(const float4*)&sB[kk][tx << 2];
      const float aa[4] = {a4.x, a4.y, a4.z, a4.w};
      const float bb[4] = {b4.x, b4.y, b4.z, b4.w};
      #pragma unroll
      for (int i = 0; i < 4; ++i)
        #pragma unroll
        for (int j = 0; j < 4; ++j) acc[i][j] += aa[i] * bb[j];
    }
  }
  #pragma unroll
  for (int i = 0; i < 4; ++i)
    #pragma unroll
    for (int j = 0; j < 4; ++j)
      g_W[st][bm + (ty << 2) + i][bn + (tx << 2) + j] = __float2half(acc[i][j]);
}

// ---- combined bias per stage ----
__global__ __launch_bounds__(256) void k_bias(const float* __restrict__ Wih,
    const float* __restrict__ bih, const float* __restrict__ bhh,
    const float* __restrict__ linb) {
  const int st = blockIdx.x, t = st >> 1, l = st & 1;
  const int tid = threadIdx.x;
  __shared__ float slb[NN];
  const bool folded = (l == 0 && t > 0);
  if (folded)
    for (int k = tid; k < NN; k += 256) slb[k] = linb[(size_t)(t - 1) * NN + k];
  __syncthreads();
  for (int m = tid; m < NN; m += 256) {
    float b = bih[(size_t)st * NN + m] + bhh[(size_t)st * NN + m];
    if (folded) {
      const float* wr = Wih + (size_t)st * NN * NN + (size_t)m * NN;
      float s0 = 0, s1 = 0, s2 = 0, s3 = 0;
      for (int k = 0; k < NN; k += 4) {
        const float4 w = *(const float4*)&wr[k];
        s0 += w.x * slb[k]; s1 += w.y * slb[k + 1];
        s2 += w.z * slb[k + 2]; s3 += w.w * slb[k + 3];
      }
      b += (s0 + s1) + (s2 + s3);
    }
    g_bias[st][m] = b;
  }
}

// ---- pipelined 16-stage scan: 256 WGs x 512 thr, 1 WG/CU, XCD-pinned stages ----
// bid: xcd = bid&7, st = 2*xcd + (bid>>7), wg = (bid>>3)&15 owns rows [64wg, 64wg+64).
// Thread (rl=tid>>3, c=tid&7): row woff+rl, combined cols [256c, 256c+256) in 32 named quads.
// Own-h link intra-XCD (critical path); upstream cross-XCD with 1-tick pipeline slack.
// One barrier/tick (double-buffered comb); 3-shfl reduce; 2 polled slots/thread.
__global__ __launch_bounds__(512)
__attribute__((amdgpu_waves_per_eu(2, 2)))
void k_phase(const float* __restrict__ x) {
  __shared__ __align__(16) unsigned char comb[2][4096];  // units: 0..127 X | 128..255 H (swz'd)
  const int tid = threadIdx.x;
  const int bid = blockIdx.x;
  const int st = ((bid & 7) << 1) + (bid >> 7);
  const int wg = (bid >> 3) & 15;
  const int woff = wg << 6;
  const int rl = tid >> 3;     // 0..63
  const int c = tid & 7;       // 0..7
  const int l = tid & 63;

#define LDW(II) ld_opaque16(&g_W[st][woff + rl][256 * c + 8 * (II)])
  u32x4 q00 = LDW(0),  q01 = LDW(1),  q02 = LDW(2),  q03 = LDW(3);
  u32x4 q04 = LDW(4),  q05 = LDW(5),  q06 = LDW(6),  q07 = LDW(7);
  u32x4 q08 = LDW(8),  q09 = LDW(9),  q10 = LDW(10), q11 = LDW(11);
  u32x4 q12 = LDW(12), q13 = LDW(13), q14 = LDW(14), q15 = LDW(15);
  u32x4 q16 = LDW(16), q17 = LDW(17), q18 = LDW(18), q19 = LDW(19);
  u32x4 q20 = LDW(20), q21 = LDW(21), q22 = LDW(22), q23 = LDW(23);
  u32x4 q24 = LDW(24), q25 = LDW(25), q26 = LDW(26), q27 = LDW(27);
  u32x4 q28 = LDW(28), q29 = LDW(29), q30 = LDW(30), q31 = LDW(31);
#undef LDW
  asm volatile("s_waitcnt vmcnt(0)" ::: "memory");
  __builtin_amdgcn_sched_barrier(0);

  const float breg = g_bias[st][woff + rl];

  // Loop-invariant comb write offsets (X at 4*tid, H at 2048+4*tid, unit-swizzled).
  const int uX = tid >> 2, off4 = (tid & 3) << 2;
  const int wbx = swzu(uX) * 16 + off4;
  const int wbh = swzu(128 + uX) * 16 + off4;
  // Loop-invariant read byte offsets base: unit 32c+II.
  const int slot_pub = (woff >> 1) + (tid >> 4);   // valid where (l&15)==0

  for (int s = 0; s < NN; ++s) {
    unsigned char* cb = comb[s & 1];
    // ---------- gather: 1 own + 1 upstream slot per thread ----------
    uint xu = 0, hu = 0;
    bool needU = (st > 0);
    bool needO = (s > 0);
    if (st == 0) {
      const float2 xv = *(const float2*)&x[(size_t)s * 8192 + 2 * tid];
      xu = pk2(xv.x, xv.y);
    }
    if (needU || needO) {
      const u64* pu = needU ? &g_S[st - 1][s][tid] : nullptr;
      const u64* po = needO ? &g_S[st][s - 1][tid] : nullptr;
      while (needU || needO) {
        u64 a = 0, b = 0;
        if (needU) a = __hip_atomic_load(pu, __ATOMIC_RELAXED, __HIP_MEMORY_SCOPE_AGENT);
        if (needO) b = __hip_atomic_load(po, __ATOMIC_RELAXED, __HIP_MEMORY_SCOPE_AGENT);
        if (needU && (a >> 32)) { xu = (uint)a; needU = false; }
        if (needO && (b >> 32)) { hu = (uint)b; needO = false; }
        if (needU || needO) __builtin_amdgcn_s_sleep(1);
      }
    }
    *(uint*)&cb[wbx] = xu;
    *(uint*)&cb[wbh] = hu;
    __syncthreads();   // the ONLY barrier per tick (comb double-buffered)

    // ---------- dot: row rl, combined cols [256c, 256c+256) ----------
    float p0 = 0.f, p1 = 0.f, p2 = 0.f, p3 = 0.f;
#define DOTSTEP(II, Q, P) { \
      const u32x4 v = *(const u32x4*)&cb[swzu(32 * c + (II)) * 16]; \
      P = __builtin_amdgcn_fdot2(as_v2h(Q.x), as_v2h(v.x), P, false); \
      P = __builtin_amdgcn_fdot2(as_v2h(Q.y), as_v2h(v.y), P, false); \
      P = __builtin_amdgcn_fdot2(as_v2h(Q.z), as_v2h(v.z), P, false); \
      P = __builtin_amdgcn_fdot2(as_v2h(Q.w), as_v2h(v.w), P, false); }
    DOTSTEP(0,  q00, p0) DOTSTEP(1,  q01, p1) DOTSTEP(2,  q02, p2) DOTSTEP(3,  q03, p3)
    DOTSTEP(4,  q04, p0) DOTSTEP(5,  q05, p1) DOTSTEP(6,  q06, p2) DOTSTEP(7,  q07, p3)
    DOTSTEP(8,  q08, p0) DOTSTEP(9,  q09, p1) DOTSTEP(10, q10, p2) DOTSTEP(11, q11, p3)
    DOTSTEP(12, q12, p0) DOTSTEP(13, q13, p1) DOTSTEP(14, q14, p2) DOTSTEP(15, q15, p3)
    DOTSTEP(16, q16, p0) DOTSTEP(17, q17, p1) DOTSTEP(18, q18, p2) DOTSTEP(19, q19, p3)
    DOTSTEP(20, q20, p0) DOTSTEP(21, q21, p1) DOTSTEP(22, q22, p2) DOTSTEP(23, q23, p3)
    DOTSTEP(24, q24, p0) DOTSTEP(25, q25, p1) DOTSTEP(26, q26, p2) DOTSTEP(27, q27, p3)
    DOTSTEP(28, q28, p0) DOTSTEP(29, q29, p1) DOTSTEP(30, q30, p2) DOTSTEP(31, q31, p3)
#undef DOTSTEP
    float p = (p0 + p1) + (p2 + p3);
    // reduce over c (lanes 8r..8r+7): 3-stage butterfly
    p += __shfl_xor(p, 1);
    p += __shfl_xor(p, 2);
    p += __shfl_xor(p, 4);
    if (c == 0) {
      const float hv = tanhf(p + breg);
      const float hp = __shfl_down(hv, 8);   // row rl+1's value (lane l+8 active here)
      if ((l & 15) == 0) {
        const u64 pv = (1ull << 32) | (u64)pk2(hv, hp);
        __hip_atomic_store(&g_S[st][s][slot_pub], pv,
                           __ATOMIC_RELAXED, __HIP_MEMORY_SCOPE_AGENT);
      }
      if (st & 1) g_Hout[st >> 1][(size_t)s * NN + woff + rl] = hv;
    }
    // no second barrier: next tick writes comb[(s+1)&1]
  }
}

// ---- epilogue: out[s][t][:] = g_Hout[t][s] @ linW[t]^T + linb[t] ----
__global__ __launch_bounds__(256) void k_out(const float* __restrict__ linW,
    const float* __restrict__ linb, float* __restrict__ out) {
  const int t = blockIdx.z;
  const float* A = g_Hout[t];
  const float* B = linW + (size_t)t * NN * NN;
  __shared__ float sA[16][68];
  __shared__ float sB[16][68];
  const int tid = threadIdx.x;
  const int tx = tid & 15, ty = tid >> 4;
  const int bm = blockIdx.y << 6, bn = blockIdx.x << 6;
  const int lm = tid & 63, lk = (tid >> 6) << 2;
  float acc[4][4] = {};
  for (int k0 = 0; k0 < NN; k0 += 16) {
    const float4 av = *(const float4*)&A[(size_t)(bm + lm) * NN + k0 + lk];
    const float4 bv = *(const float4*)&B[(size_t)(bn + lm) * NN + k0 + lk];
    __syncthreads();
    sA[lk + 0][lm] = av.x; sA[lk + 1][lm] = av.y; sA[lk + 2][lm] = av.z; sA[lk + 3][lm] = av.w;
    sB[lk + 0][lm] = bv.x; sB[lk + 1][lm] = bv.y; sB[lk + 2][lm] = bv.z; sB[lk + 3][lm] = bv.w;
    __syncthreads();
    #pragma unroll
    for (int kk = 0; kk < 16; ++kk) {
      const float4 a4 = *(const float4*)&sA[kk][ty << 2];
      const float4 b4 = *(const float4*)&sB[kk][tx << 2];
      const float aa[4] = {a4.x, a4.y, a4.z, a4.w};
      const float bb[4] = {b4.x, b4.y, b4.z, b4.w};
      #pragma unroll
      for (int i = 0; i < 4; ++i)
        #pragma unroll
        for (int j = 0; j < 4; ++j) acc[i][j] += aa[i] * bb[j];
    }
  }
  const int n0 = bn + (tx << 2);
  float bias[4];
  #pragma unroll
  for (int j = 0; j < 4; ++j) bias[j] = linb[(size_t)t * NN + n0 + j];
  #pragma unroll
  for (int i = 0; i < 4; ++i) {
    const int m = bm + (ty << 2) + i;
    float4 o;
    o.x = acc[i][0] + bias[0]; o.y = acc[i][1] + bias[1];
    o.z = acc[i][2] + bias[2]; o.w = acc[i][3] + bias[3];
    *(float4*)&out[(size_t)m * 8192 + (size_t)t * NN + n0] = o;
  }
}

extern "C" void kernel_launch(void* const* d_in, const int* in_sizes, int n_in,
                              void* d_out, int out_size, void* d_ws, size_t ws_size,
                              hipStream_t stream) {
  (void)in_sizes; (void)n_in; (void)out_size; (void)d_ws; (void)ws_size;
  const float* x    = (const float*)d_in[0];
  const float* Wih  = (const float*)d_in[1];
  const float* Whh  = (const float*)d_in[2];
  const float* bih  = (const float*)d_in[3];
  const float* bhh  = (const float*)d_in[4];
  const float* linW = (const float*)d_in[5];
  const float* linb = (const float*)d_in[6];
  float* out = (float*)d_out;

  k_init<<<2048, 256, 0, stream>>>();
  k_pack<<<2048, 256, 0, stream>>>(Wih, Whh);
  k_fold<<<dim3(16, 16, 7), 256, 0, stream>>>(Wih, linW);
  k_bias<<<16, 256, 0, stream>>>(Wih, bih, bhh, linb);
  k_phase<<<256, 512, 0, stream>>>(x);
  k_out<<<dim3(16, 16, 8), 256, 0, stream>>>(linW, linb, out);
}

// Round 12
// 2486.101 us; speedup vs baseline: 9.0698x; 1.3592x over previous
//
#include <hip/hip_runtime.h>
#include <hip/hip_fp16.h>

#define NN 1024
#define NST 16
#define WPS 16                  // WGs per stage
#define WROWS 64                // rows per WG

typedef _Float16 v2h __attribute__((ext_vector_type(2)));
typedef unsigned int uint;
typedef unsigned long long u64;
typedef unsigned int u32x4 __attribute__((ext_vector_type(4)));

// Static device scratch.
__device__ __half g_W[NST][NN][2048];      // per stage row: [Wih_eff(1024) | Whh(1024)] fp16
__device__ float g_bias[NST][NN];          // combined bias fp32
__device__ u64 g_S[NST][NN][512];          // slot q = {1<<32 | fp16 h[2q+1],h[2q]}
__device__ float g_Hout[8][NN * NN];       // h of odd stages (pre-linear), fp32

__device__ __forceinline__ v2h as_v2h(uint u) {
  union { uint u; v2h h; } c; c.u = u; return c.h;
}
__device__ __forceinline__ uint pk2(float a, float b) {
  union { v2h h; uint u; } c; c.h.x = (_Float16)a; c.h.y = (_Float16)b; return c.u;
}
// 16B-unit swizzle: low3' = (u + (u>>3)) & 7. Read pattern u = 8c+jj (c=0..15):
// fixed jj -> low3' = (jj+c)&7 cycles the 8 bank groups (2 units/group, free 2-way).
__device__ __forceinline__ int swzu(int u) {
  return (u & ~7) | ((u + (u >> 3)) & 7);
}
// Opaque (non-rematerializable) 16B load.
__device__ __forceinline__ u32x4 ld_opaque16(const __half* p) {
  u32x4 r;
  asm volatile("global_load_dwordx4 %0, %1, off" : "=v"(r) : "v"(p));
  return r;
}
__device__ __forceinline__ float fdot4(u32x4 w, u32x4 v, float a) {
  a = __builtin_amdgcn_fdot2(as_v2h(w.x), as_v2h(v.x), a, false);
  a = __builtin_amdgcn_fdot2(as_v2h(w.y), as_v2h(v.y), a, false);
  a = __builtin_amdgcn_fdot2(as_v2h(w.z), as_v2h(v.z), a, false);
  a = __builtin_amdgcn_fdot2(as_v2h(w.w), as_v2h(v.w), a, false);
  return a;
}

// ---- zero exchange slots (every launch, replay determinism) ----
__global__ void k_init() {
  const size_t n = (size_t)NST * NN * 512;
  size_t i = (size_t)blockIdx.x * blockDim.x + threadIdx.x;
  const size_t stride = (size_t)gridDim.x * blockDim.x;
  u64* p = &g_S[0][0][0];
  for (; i < n; i += stride) p[i] = 0ull;
}

// ---- pack Whh (all stages) and Wih (non-folded stages) to fp16 ----
__global__ void k_pack(const float* __restrict__ Wih, const float* __restrict__ Whh) {
  const size_t total = (size_t)NST * NN * NN;
  size_t i = (size_t)blockIdx.x * blockDim.x + threadIdx.x;
  const size_t stride = (size_t)gridDim.x * blockDim.x;
  for (; i < total; i += stride) {
    const int st = (int)(i >> 20);
    const int m = (int)(i >> 10) & 1023;
    const int k = (int)i & 1023;
    g_W[st][m][1024 + k] = __float2half(Whh[i]);
    const int t = st >> 1, l = st & 1;
    if (l == 1 || t == 0) g_W[st][m][k] = __float2half(Wih[i]);
  }
}

// ---- fold: W'(st=2t) = Wih[st] @ linW[t-1] ----
__global__ __launch_bounds__(256) void k_fold(const float* __restrict__ Wih,
                                              const float* __restrict__ linW) {
  const int tm1 = blockIdx.z;
  const int st = (tm1 + 1) * 2;
  const float* A = Wih + (size_t)st * NN * NN;
  const float* B = linW + (size_t)tm1 * NN * NN;
  __shared__ float sA[16][68];
  __shared__ float sB[16][68];
  const int tid = threadIdx.x;
  const int tx = tid & 15, ty = tid >> 4;
  const int bm = blockIdx.y << 6, bn = blockIdx.x << 6;
  const int lm = tid & 63, lk = (tid >> 6) << 2;
  const int rr = tid >> 4, c4 = (tid & 15) << 2;
  float acc[4][4] = {};
  for (int k0 = 0; k0 < NN; k0 += 16) {
    const float4 av = *(const float4*)&A[(size_t)(bm + lm) * NN + k0 + lk];
    const float4 bv = *(const float4*)&B[(size_t)(k0 + rr) * NN + bn + c4];
    __syncthreads();
    sA[lk + 0][lm] = av.x; sA[lk + 1][lm] = av.y; sA[lk + 2][lm] = av.z; sA[lk + 3][lm] = av.w;
    sB[rr][c4 + 0] = bv.x; sB[rr][c4 + 1] = bv.y; sB[rr][c4 + 2] = bv.z; sB[rr][c4 + 3] = bv.w;
    __syncthreads();
    #pragma unroll
    for (int kk = 0; kk < 16; ++kk) {
      const float4 a4 = *(const float4*)&sA[kk][ty << 2];
      const float4 b4 = *(const float4*)&sB[kk][tx << 2];
      const float aa[4] = {a4.x, a4.y, a4.z, a4.w};
      const float bb[4] = {b4.x, b4.y, b4.z, b4.w};
      #pragma unroll
      for (int i = 0; i < 4; ++i)
        #pragma unroll
        for (int j = 0; j < 4; ++j) acc[i][j] += aa[i] * bb[j];
    }
  }
  #pragma unroll
  for (int i = 0; i < 4; ++i)
    #pragma unroll
    for (int j = 0; j < 4; ++j)
      g_W[st][bm + (ty << 2) + i][bn + (tx << 2) + j] = __float2half(acc[i][j]);
}

// ---- combined bias per stage ----
__global__ __launch_bounds__(256) void k_bias(const float* __restrict__ Wih,
    const float* __restrict__ bih, const float* __restrict__ bhh,
    const float* __restrict__ linb) {
  const int st = blockIdx.x, t = st >> 1, l = st & 1;
  const int tid = threadIdx.x;
  __shared__ float slb[NN];
  const bool folded = (l == 0 && t > 0);
  if (folded)
    for (int k = tid; k < NN; k += 256) slb[k] = linb[(size_t)(t - 1) * NN + k];
  __syncthreads();
  for (int m = tid; m < NN; m += 256) {
    float b = bih[(size_t)st * NN + m] + bhh[(size_t)st * NN + m];
    if (folded) {
      const float* wr = Wih + (size_t)st * NN * NN + (size_t)m * NN;
      float s0 = 0, s1 = 0, s2 = 0, s3 = 0;
      for (int k = 0; k < NN; k += 4) {
        const float4 w = *(const float4*)&wr[k];
        s0 += w.x * slb[k]; s1 += w.y * slb[k + 1];
        s2 += w.z * slb[k + 2]; s3 += w.w * slb[k + 3];
      }
      b += (s0 + s1) + (s2 + s3);
    }
    g_bias[st][m] = b;
  }
}

// ---- pipelined 16-stage scan: 256 WGs x 512 thr, 1 WG/CU, XCD-pinned stages ----
// Thread (i=tid>>4, c=tid&15): rows woff+2i, woff+2i+1; cols [64c,64c+64) of X AND of H.
// Split-phase tick: resolve upstream -> write X -> bar1 -> X-dot (own-h RT hides here)
// -> poll own -> write H -> bar2 -> H-dot -> 4-stage shfl reduce x2 -> publish pair.
__global__ __launch_bounds__(512)
__attribute__((amdgpu_waves_per_eu(2, 2)))
void k_phase(const float* __restrict__ x) {
  __shared__ __align__(16) unsigned char comb[2][4096];  // units 0..127 X | 128..255 H (swz'd)
  const int tid = threadIdx.x;
  const int bid = blockIdx.x;
  const int st = ((bid & 7) << 1) + (bid >> 7);
  const int wg = (bid >> 3) & 15;
  const int woff = wg << 6;
  const int i = tid >> 4;      // row-pair 0..31
  const int c = tid & 15;      // col chunk 0..15

#define LDX(RR, JJ) ld_opaque16(&g_W[st][woff + 2 * i + (RR)][64 * c + 8 * (JJ)])
#define LDH(RR, JJ) ld_opaque16(&g_W[st][woff + 2 * i + (RR)][1024 + 64 * c + 8 * (JJ)])
  u32x4 x00 = LDX(0,0), x01 = LDX(0,1), x02 = LDX(0,2), x03 = LDX(0,3);
  u32x4 x04 = LDX(0,4), x05 = LDX(0,5), x06 = LDX(0,6), x07 = LDX(0,7);
  u32x4 x10 = LDX(1,0), x11 = LDX(1,1), x12 = LDX(1,2), x13 = LDX(1,3);
  u32x4 x14 = LDX(1,4), x15 = LDX(1,5), x16 = LDX(1,6), x17 = LDX(1,7);
  u32x4 h00 = LDH(0,0), h01 = LDH(0,1), h02 = LDH(0,2), h03 = LDH(0,3);
  u32x4 h04 = LDH(0,4), h05 = LDH(0,5), h06 = LDH(0,6), h07 = LDH(0,7);
  u32x4 h10 = LDH(1,0), h11 = LDH(1,1), h12 = LDH(1,2), h13 = LDH(1,3);
  u32x4 h14 = LDH(1,4), h15 = LDH(1,5), h16 = LDH(1,6), h17 = LDH(1,7);
#undef LDX
#undef LDH
  asm volatile("s_waitcnt vmcnt(0)" ::: "memory");
  __builtin_amdgcn_sched_barrier(0);

  const float2 breg = *(const float2*)&g_bias[st][woff + 2 * i];

  // Loop-invariant comb byte offsets (write: unit tid>>2, dword tid&3; swizzled).
  const int uW = tid >> 2, off4 = (tid & 3) << 2;
  const int wbx = swzu(uW) * 16 + off4;
  const int wbh = swzu(128 + uW) * 16 + off4;
  const int slot_pub = (woff >> 1) + i;     // publisher: c==0

  for (int s = 0; s < NN; ++s) {
    unsigned char* cb = comb[s & 1];
    // ---------- phase A: upstream (ready ~1 tick early at steady state) ----------
    uint xu = 0;
    if (st == 0) {
      const float2 xv = *(const float2*)&x[(size_t)s * 8192 + 2 * tid];
      xu = pk2(xv.x, xv.y);
    } else {
      const u64* pu = &g_S[st - 1][s][tid];
      for (;;) {
        const u64 a = __hip_atomic_load(pu, __ATOMIC_RELAXED, __HIP_MEMORY_SCOPE_AGENT);
        if (a >> 32) { xu = (uint)a; break; }
        __builtin_amdgcn_s_sleep(1);
      }
    }
    *(uint*)&cb[wbx] = xu;
    __syncthreads();   // bar1: X half ready

    // ---------- X-dot (own-h round trip hides under this) ----------
    float p0 = 0.f, p1 = 0.f;
#define XSTEP(JJ, Q0, Q1) { \
      const u32x4 v = *(const u32x4*)&cb[swzu(8 * c + (JJ)) * 16]; \
      p0 = fdot4(Q0, v, p0); p1 = fdot4(Q1, v, p1); }
    XSTEP(0, x00, x10) XSTEP(1, x01, x11) XSTEP(2, x02, x12) XSTEP(3, x03, x13)
    XSTEP(4, x04, x14) XSTEP(5, x05, x15) XSTEP(6, x06, x16) XSTEP(7, x07, x17)
#undef XSTEP

    // ---------- phase B: own h(s-1) ----------
    uint hu = 0;
    if (s > 0) {
      const u64* po = &g_S[st][s - 1][tid];
      for (;;) {
        const u64 b = __hip_atomic_load(po, __ATOMIC_RELAXED, __HIP_MEMORY_SCOPE_AGENT);
        if (b >> 32) { hu = (uint)b; break; }
        __builtin_amdgcn_s_sleep(1);
      }
    }
    *(uint*)&cb[wbh] = hu;
    __syncthreads();   // bar2: H half ready

    // ---------- H-dot ----------
#define HSTEP(JJ, Q0, Q1) { \
      const u32x4 v = *(const u32x4*)&cb[swzu(128 + 8 * c + (JJ)) * 16]; \
      p0 = fdot4(Q0, v, p0); p1 = fdot4(Q1, v, p1); }
    HSTEP(0, h00, h10) HSTEP(1, h01, h11) HSTEP(2, h02, h12) HSTEP(3, h03, h13)
    HSTEP(4, h04, h14) HSTEP(5, h05, h15) HSTEP(6, h06, h16) HSTEP(7, h07, h17)
#undef HSTEP

    // reduce over c (16 lanes): 4-stage butterfly for both rows
    p0 += __shfl_xor(p0, 1); p1 += __shfl_xor(p1, 1);
    p0 += __shfl_xor(p0, 2); p1 += __shfl_xor(p1, 2);
    p0 += __shfl_xor(p0, 4); p1 += __shfl_xor(p1, 4);
    p0 += __shfl_xor(p0, 8); p1 += __shfl_xor(p1, 8);
    if (c == 0) {
      const float hv0 = tanhf(p0 + breg.x);
      const float hv1 = tanhf(p1 + breg.y);
      const u64 pv = (1ull << 32) | (u64)pk2(hv0, hv1);
      __hip_atomic_store(&g_S[st][s][slot_pub], pv,
                         __ATOMIC_RELAXED, __HIP_MEMORY_SCOPE_AGENT);
      if (st & 1)
        *(float2*)&g_Hout[st >> 1][(size_t)s * NN + woff + 2 * i] =
            make_float2(hv0, hv1);
    }
    // no trailing barrier: tick s+1 writes comb[(s+1)&1]; X/H halves of comb[s&1]
    // are next written at ticks s+2 (after bar2(s+1)/bar1(s+2)) — separated by barriers.
  }
}

// ---- epilogue: out[s][t][:] = g_Hout[t][s] @ linW[t]^T + linb[t] ----
__global__ __launch_bounds__(256) void k_out(const float* __restrict__ linW,
    const float* __restrict__ linb, float* __restrict__ out) {
  const int t = blockIdx.z;
  const float* A = g_Hout[t];
  const float* B = linW + (size_t)t * NN * NN;
  __shared__ float sA[16][68];
  __shared__ float sB[16][68];
  const int tid = threadIdx.x;
  const int tx = tid & 15, ty = tid >> 4;
  const int bm = blockIdx.y << 6, bn = blockIdx.x << 6;
  const int lm = tid & 63, lk = (tid >> 6) << 2;
  float acc[4][4] = {};
  for (int k0 = 0; k0 < NN; k0 += 16) {
    const float4 av = *(const float4*)&A[(size_t)(bm + lm) * NN + k0 + lk];
    const float4 bv = *(const float4*)&B[(size_t)(bn + lm) * NN + k0 + lk];
    __syncthreads();
    sA[lk + 0][lm] = av.x; sA[lk + 1][lm] = av.y; sA[lk + 2][lm] = av.z; sA[lk + 3][lm] = av.w;
    sB[lk + 0][lm] = bv.x; sB[lk + 1][lm] = bv.y; sB[lk + 2][lm] = bv.z; sB[lk + 3][lm] = bv.w;
    __syncthreads();
    #pragma unroll
    for (int kk = 0; kk < 16; ++kk) {
      const float4 a4 = *(const float4*)&sA[kk][ty << 2];
      const float4 b4 = *(const float4*)&sB[kk][tx << 2];
      const float aa[4] = {a4.x, a4.y, a4.z, a4.w};
      const float bb[4] = {b4.x, b4.y, b4.z, b4.w};
      #pragma unroll
      for (int i = 0; i < 4; ++i)
        #pragma unroll
        for (int j = 0; j < 4; ++j) acc[i][j] += aa[i] * bb[j];
    }
  }
  const int n0 = bn + (tx << 2);
  float bias[4];
  #pragma unroll
  for (int j = 0; j < 4; ++j) bias[j] = linb[(size_t)t * NN + n0 + j];
  #pragma unroll
  for (int i = 0; i < 4; ++i) {
    const int m = bm + (ty << 2) + i;
    float4 o;
    o.x = acc[i][0] + bias[0]; o.y = acc[i][1] + bias[1];
    o.z = acc[i][2] + bias[2]; o.w = acc[i][3] + bias[3];
    *(float4*)&out[(size_t)m * 8192 + (size_t)t * NN + n0] = o;
  }
}

extern "C" void kernel_launch(void* const* d_in, const int* in_sizes, int n_in,
                              void* d_out, int out_size, void* d_ws, size_t ws_size,
                              hipStream_t stream) {
  (void)in_sizes; (void)n_in; (void)out_size; (void)d_ws; (void)ws_size;
  const float* x    = (const float*)d_in[0];
  const float* Wih  = (const float*)d_in[1];
  const float* Whh  = (const float*)d_in[2];
  const float* bih  = (const float*)d_in[3];
  const float* bhh  = (const float*)d_in[4];
  const float* linW = (const float*)d_in[5];
  const float* linb = (const float*)d_in[6];
  float* out = (float*)d_out;

  k_init<<<2048, 256, 0, stream>>>();
  k_pack<<<2048, 256, 0, stream>>>(Wih, Whh);
  k_fold<<<dim3(16, 16, 7), 256, 0, stream>>>(Wih, linW);
  k_bias<<<16, 256, 0, stream>>>(Wih, bih, bhh, linb);
  k_phase<<<256, 512, 0, stream>>>(x);
  k_out<<<dim3(16, 16, 8), 256, 0, stream>>>(linW, linb, out);
}